// Round 7
// baseline (179.662 us; speedup 1.0000x reference)
//
#include <hip/hip_runtime.h>

typedef _Float16 f16;
typedef _Float16 f16x8 __attribute__((ext_vector_type(8)));
typedef _Float16 f16x4 __attribute__((ext_vector_type(4)));
typedef float    f32x4 __attribute__((ext_vector_type(4)));

// Problem: B=2, S=2048, E=2048, H=16, HKV=4, D=128, WINDOW=256
// Reference quirk: only q heads 0..3 used (q also indexed by idx); Wo pre-folds
// over the 4 heads per group: Wr[e,g*128+d] = sum_j Wo[e,(4g+j)*128+d].
//
// R12: R6 post-mortem: total 177.7; all our kernels < 40.7us (fills clog
// top-5). Change with the cleanest arithmetic: out_gemm 64x128 -> 128x128
// tile (per-wave 8 ds_read per 16 MFMA instead of 6 per 8; grid 512 = exactly
// 2 blocks/CU, LDS 64KB). qkv/attn/cvt unchanged (attn occupancy fix needs
// counters first; qkv at 128^2 would be an unbalanced 384-grid).

__device__ __forceinline__ void load_lds16(const void* g, void* l) {
    __builtin_amdgcn_global_load_lds(
        (__attribute__((address_space(1))) void*)(g),
        (__attribute__((address_space(3))) void*)(l), 16, 0, 0);
}

// ---------------------------------------------------------------------------
// Pre-pass: f32->f16 convert + pack.
//  blk [0,4096):    X  -> Xp  (64 panels x 64 ktiles, tile 64x32)
//  blk [4096,5632): W  -> Wp  (12 panels x 64 ktiles, tile 128x32)
//  blk [5632,6144): Wo -> Wrp (16 panels x 16 ktiles, tile 128x32, GQA-folded)
// ---------------------------------------------------------------------------
__global__ __launch_bounds__(256)
void cvt_pack(const float* __restrict__ X, const float* __restrict__ Wq,
              const float* __restrict__ Wk, const float* __restrict__ Wv,
              const float* __restrict__ Wo,
              f16* __restrict__ Xp, f16* __restrict__ Wp, f16* __restrict__ Wrp)
{
    const int blk = blockIdx.x, tid = threadIdx.x;
    if (blk < 4096) {
        int cid = blk * 256 + tid;
        int tile = cid >> 8, wc = cid & 255;
        int row = wc >> 2, kc = wc & 3;
        int m = ((tile >> 6) << 6) + row;
        int t = tile & 63;
        int sk = t * 32 + ((kc ^ ((row >> 1) & 3)) << 3);
        const float* s = X + (size_t)m * 2048 + sk;
        float4 a = *(const float4*)(s);
        float4 b = *(const float4*)(s + 4);
        f16x8 o;
        o[0]=(f16)a.x; o[1]=(f16)a.y; o[2]=(f16)a.z; o[3]=(f16)a.w;
        o[4]=(f16)b.x; o[5]=(f16)b.y; o[6]=(f16)b.z; o[7]=(f16)b.w;
        *(f16x8*)(Xp + (size_t)cid * 8) = o;
    } else if (blk < 5632) {
        int wid = (blk - 4096) * 256 + tid;
        int tile = wid >> 9, wc = wid & 511;
        int row = wc >> 2, kc = wc & 3;
        int n = ((tile >> 6) << 7) + row;
        int t = tile & 63;
        int sk = t * 32 + ((kc ^ ((row >> 1) & 3)) << 3);
        const float* src = (n < 512)  ? (Wq + (size_t)n * 2048 + sk)
                         : (n < 1024) ? (Wk + (size_t)(n - 512) * 2048 + sk)
                                      : (Wv + (size_t)(n - 1024) * 2048 + sk);
        float4 a = *(const float4*)(src);
        float4 b = *(const float4*)(src + 4);
        f16x8 o;
        o[0]=(f16)a.x; o[1]=(f16)a.y; o[2]=(f16)a.z; o[3]=(f16)a.w;
        o[4]=(f16)b.x; o[5]=(f16)b.y; o[6]=(f16)b.z; o[7]=(f16)b.w;
        *(f16x8*)(Wp + (size_t)wid * 8) = o;
    } else {
        int rid = (blk - 5632) * 256 + tid;
        int tile = rid >> 9, wc = rid & 511;
        int row = wc >> 2, kc = wc & 3;
        int e = ((tile >> 4) << 7) + row;
        int t = tile & 15;
        int cc = kc ^ ((row >> 1) & 3);
        int c = t * 32 + (cc << 3);
        int g = c >> 7, d0 = c & 127;
        const float* src = Wo + (size_t)e * 2048 + g * 512 + d0;
        float4 a0 = *(const float4*)(src);
        float4 a1 = *(const float4*)(src + 128);
        float4 a2 = *(const float4*)(src + 256);
        float4 a3 = *(const float4*)(src + 384);
        float4 b0 = *(const float4*)(src + 4);
        float4 b1 = *(const float4*)(src + 132);
        float4 b2 = *(const float4*)(src + 260);
        float4 b3 = *(const float4*)(src + 388);
        f16x8 o;
        o[0] = (f16)(a0.x + a1.x + a2.x + a3.x);
        o[1] = (f16)(a0.y + a1.y + a2.y + a3.y);
        o[2] = (f16)(a0.z + a1.z + a2.z + a3.z);
        o[3] = (f16)(a0.w + a1.w + a2.w + a3.w);
        o[4] = (f16)(b0.x + b1.x + b2.x + b3.x);
        o[5] = (f16)(b0.y + b1.y + b2.y + b3.y);
        o[6] = (f16)(b0.z + b1.z + b2.z + b3.z);
        o[7] = (f16)(b0.w + b1.w + b2.w + b3.w);
        *(f16x8*)(Wrp + (size_t)rid * 8) = o;
    }
}

#define STAGE3(t, buf)                                          \
    {                                                           \
        load_lds16(gs0 + (size_t)(t) * st0, &S[buf][lo0]);      \
        load_lds16(gs1 + (size_t)(t) * st1, &S[buf][lo1]);      \
        load_lds16(gs2 + (size_t)(t) * st2, &S[buf][lo2]);      \
    }

#define PIPE_WAIT(t, NSTEP)                                              \
    if ((t) < (NSTEP)-2) {                                               \
        asm volatile("s_waitcnt vmcnt(6) lgkmcnt(0)" ::: "memory");      \
    } else if ((t) == (NSTEP)-2) {                                       \
        asm volatile("s_waitcnt vmcnt(3) lgkmcnt(0)" ::: "memory");      \
    } else {                                                             \
        asm volatile("s_waitcnt vmcnt(0) lgkmcnt(0)" ::: "memory");      \
    }                                                                    \
    __builtin_amdgcn_s_barrier();

// ---------------------------------------------------------------------------
// Merged QKV GEMM: M=4096, N=1536, K=2048. Packed inputs. Tile 64x128.
// n in [0,512): Q -> (B,4,S,D); [512,1024): K -> attn-packed tiles;
// [1024,1536): V -> attn-packed tiles.
// Packed K:  Kp[bg][t][s&127][ ((d>>3)^(s&15))*8 + (d&7) ]
// Packed V:  Vp[bg][t][d]    [ ((s7>>3)^(d&15))*8 + (s7&7) ]  (s7 = s&127)
// ---------------------------------------------------------------------------
__global__ __launch_bounds__(256)
void qkv_gemm(const f16* __restrict__ Xp, const f16* __restrict__ Wp,
              f16* __restrict__ Qo, f16* __restrict__ Ko, f16* __restrict__ Vo)
{
    const int NSTEP = 64;
    __shared__ __align__(16) f16 S[4][6144];

    const int tid = threadIdx.x;
    const int wave = tid >> 6, lane = tid & 63;
    const int lrow = lane & 15, lquad = lane >> 4;
    const int wr = wave >> 1, wc = wave & 1;

    int id = (int)blockIdx.x;                 // 768 = 8 * 96
    int id2 = (id & 7) * 96 + (id >> 3);      // bijective XCD swizzle
    int bx = id2 % 12, by = id2 / 12;
    const int m0 = by * 64, n0 = bx * 128;

    const f16* gs0; const f16* gs1; const f16* gs2;
    size_t st0, st1, st2;
    int lo0, lo1, lo2;
    {
        int sb;
        sb = (wave * 3 + 0) * 64; lo0 = (sb + lane) * 8;
        if (sb < 256) { gs0 = Xp + (size_t)by * 131072 + lo0;          st0 = 2048; }
        else          { gs0 = Wp + (size_t)bx * 262144 + (lo0 - 2048); st0 = 4096; }
        sb = (wave * 3 + 1) * 64; lo1 = (sb + lane) * 8;
        if (sb < 256) { gs1 = Xp + (size_t)by * 131072 + lo1;          st1 = 2048; }
        else          { gs1 = Wp + (size_t)bx * 262144 + (lo1 - 2048); st1 = 4096; }
        sb = (wave * 3 + 2) * 64; lo2 = (sb + lane) * 8;
        if (sb < 256) { gs2 = Xp + (size_t)by * 131072 + lo2;          st2 = 2048; }
        else          { gs2 = Wp + (size_t)bx * 262144 + (lo2 - 2048); st2 = 4096; }
    }

    int aoff[2], boff[4];
#pragma unroll
    for (int t = 0; t < 2; t++) {
        int ra = wr * 32 + t * 16 + lrow;
        aoff[t] = ra * 32 + ((lquad ^ ((ra >> 1) & 3)) << 3);
    }
#pragma unroll
    for (int t = 0; t < 4; t++) {
        int rb = wc * 64 + t * 16 + lrow;
        boff[t] = 2048 + rb * 32 + ((lquad ^ ((rb >> 1) & 3)) << 3);
    }

    f32x4 acc[2][4];
    const f32x4 z4 = {0.f, 0.f, 0.f, 0.f};
#pragma unroll
    for (int i = 0; i < 2; i++) for (int j = 0; j < 4; j++) acc[i][j] = z4;

    STAGE3(0, 0); STAGE3(1, 1); STAGE3(2, 2);

    int buf = 0;
    for (int t = 0; t < NSTEP; ++t) {
        PIPE_WAIT(t, NSTEP);
        if (t < NSTEP - 3) STAGE3(t + 3, (buf + 3) & 3);
        f16x8 af[2], bf[4];
#pragma unroll
        for (int mt = 0; mt < 2; mt++) af[mt] = *(const f16x8*)(&S[buf][aoff[mt]]);
#pragma unroll
        for (int nt = 0; nt < 4; nt++) bf[nt] = *(const f16x8*)(&S[buf][boff[nt]]);
#pragma unroll
        for (int mt = 0; mt < 2; mt++)
#pragma unroll
            for (int nt = 0; nt < 4; nt++)
                acc[mt][nt] = __builtin_amdgcn_mfma_f32_16x16x32_f16(af[mt], bf[nt], acc[mt][nt], 0, 0, 0);
        buf = (buf + 1) & 3;
    }

    const int z = n0 >> 9;
    const int hh = (n0 >> 7) & 3;
    if (z == 0) {
        // Q: (B,4,S,D) row-major
#pragma unroll
        for (int mt = 0; mt < 2; mt++) {
            int mbase = m0 + wr * 32 + mt * 16 + lquad * 4;
#pragma unroll
            for (int r = 0; r < 4; r++) {
                int m = mbase + r;
                int bb = m >> 11, s = m & 2047;
#pragma unroll
                for (int nt = 0; nt < 4; nt++) {
                    int d = wc * 64 + nt * 16 + lrow;
                    Qo[(size_t)(((bb * 4 + hh) << 11) + s) * 128 + d] = (f16)acc[mt][nt][r];
                }
            }
        }
    } else if (z == 1) {
        // K: attn-packed swizzled tiles
#pragma unroll
        for (int mt = 0; mt < 2; mt++) {
            int mbase = m0 + wr * 32 + mt * 16 + lquad * 4;
#pragma unroll
            for (int r = 0; r < 4; r++) {
                int m = mbase + r;
                int bb = m >> 11, s = m & 2047;
                size_t base = ((size_t)(bb * 4 + hh) * 16 + (s >> 7)) * 16384
                            + (size_t)(s & 127) * 128;
#pragma unroll
                for (int nt = 0; nt < 4; nt++) {
                    int d = wc * 64 + nt * 16 + lrow;
                    Ko[base + (((d >> 3) ^ (s & 15)) << 3) + (d & 7)] = (f16)acc[mt][nt][r];
                }
            }
        }
    } else {
        // V: attn-packed swizzled tiles (f16x4 over 4 consecutive s)
#pragma unroll
        for (int mt = 0; mt < 2; mt++) {
            int mbase = m0 + wr * 32 + mt * 16 + lquad * 4;
            int bb = mbase >> 11, s = mbase & 2047;
            int tt = s >> 7, sl = s & 127;
            int gsx = sl >> 3, j0 = sl & 7;     // j0 in {0,4}; granule-constant
#pragma unroll
            for (int nt = 0; nt < 4; nt++) {
                int d = wc * 64 + nt * 16 + lrow;
                f16x4 pk;
#pragma unroll
                for (int r = 0; r < 4; r++) pk[r] = (f16)acc[mt][nt][r];
                *(f16x4*)(Vo + ((size_t)(bb * 4 + hh) * 16 + tt) * 16384
                             + (size_t)d * 128 + ((gsx ^ (d & 15)) << 3) + j0) = pk;
            }
        }
    }
}

// ---------------------------------------------------------------------------
// Sliding-window attention. 4 waves/block, 64 q-rows/block, one (b,g).
// Grid 256; bg = blockIdx.x & 7 pins each head to one XCD.
// K/V: packed swizzled 32KB tiles, staged as linear DMA, double-buffered.
// AO written in out_gemm's packed A layout.
// ---------------------------------------------------------------------------
__global__ __launch_bounds__(256)
void attn_win(const f16* __restrict__ Q, const f16* __restrict__ Kp,
              const f16* __restrict__ Vp, f16* __restrict__ AO)
{
    const int h = blockIdx.x;
    const int bg = h & 7, qt = h >> 3;
    const int b = bg >> 2, g = bg & 3;
    const int qbase = qt * 64;
    const int tid = threadIdx.x;
    const int wave = tid >> 6, lane = tid & 63;
    const int lrow = lane & 15, lquad = lane >> 4;
    const int qw = qbase + wave * 16;

    const f16* Qb = Q  + (size_t)bg * (2048 * 128);
    const f16* Kt = Kp + (size_t)bg * (2048 * 128);
    const f16* Vt = Vp + (size_t)bg * (2048 * 128);

    __shared__ __align__(16) f16 Ks[2][16384];
    __shared__ __align__(16) f16 Vs[2][16384];
    __shared__ __align__(16) f16 Pl[4][2048];

    f16x8 qf[4];
#pragma unroll
    for (int ks = 0; ks < 4; ks++)
        qf[ks] = *(const f16x8*)(Qb + (size_t)(qw + lrow) * 128 + ks * 32 + lquad * 8);

    float m_i[4], l_i[4];
    f32x4 oa[8];
    const f32x4 z4 = {0.f, 0.f, 0.f, 0.f};
#pragma unroll
    for (int r = 0; r < 4; r++) { m_i[r] = -30000.f; l_i[r] = 0.f; }
#pragma unroll
    for (int nt = 0; nt < 8; nt++) oa[nt] = z4;

    const int tstart = (qbase >= 256) ? ((qbase - 255) >> 7) : 0;
    const int tend = (qbase + 63) >> 7;

    {   // prologue: stage tile tstart into buf 0 (32 linear DMA instrs)
        const f16* ksrc = Kt + (size_t)tstart * 16384;
        const f16* vsrc = Vt + (size_t)tstart * 16384;
#pragma unroll
        for (int j = 0; j < 8; j++) {
            load_lds16(ksrc + (j * 256 + tid) * 8, &Ks[0][(j * 256 + tid) * 8]);
            load_lds16(vsrc + (j * 256 + tid) * 8, &Vs[0][(j * 256 + tid) * 8]);
        }
    }

    int buf = 0;
    for (int t = tstart; t <= tend; ++t) {
        if (t < tend) {       // prefetch next tile into other buffer
            const f16* ksrc = Kt + (size_t)(t + 1) * 16384;
            const f16* vsrc = Vt + (size_t)(t + 1) * 16384;
#pragma unroll
            for (int j = 0; j < 8; j++) {
                load_lds16(ksrc + (j * 256 + tid) * 8, &Ks[buf ^ 1][(j * 256 + tid) * 8]);
                load_lds16(vsrc + (j * 256 + tid) * 8, &Vs[buf ^ 1][(j * 256 + tid) * 8]);
            }
            asm volatile("s_waitcnt vmcnt(16)" ::: "memory");  // tile t ready
        } else {
            asm volatile("s_waitcnt vmcnt(0)" ::: "memory");
        }
        __builtin_amdgcn_s_barrier();

        const int kt = t * 128;
        f32x4 sc[8];
#pragma unroll
        for (int nt = 0; nt < 8; nt++) sc[nt] = z4;
#pragma unroll
        for (int nt = 0; nt < 8; nt++) {
#pragma unroll
            for (int ks = 0; ks < 4; ks++) {
                f16x8 kf = *(const f16x8*)(&Ks[buf][(nt * 16 + lrow) * 128
                                  + (((ks * 4 + lquad) ^ lrow) << 3)]);
                sc[nt] = __builtin_amdgcn_mfma_f32_16x16x32_f16(qf[ks], kf, sc[nt], 0, 0, 0);
            }
        }
#pragma unroll
        for (int r = 0; r < 4; r++) {
            const int qi = qw + lquad * 4 + r;
            float rmax = -60000.f;
#pragma unroll
            for (int nt = 0; nt < 8; nt++) {
                int kj = kt + nt * 16 + lrow;
                float sval = sc[nt][r];
                bool ok = (kj <= qi) && (kj + 256 > qi);
                sval = ok ? sval : -60000.f;
                sc[nt][r] = sval;
                rmax = fmaxf(rmax, sval);
            }
            rmax = fmaxf(rmax, __shfl_xor(rmax, 1));
            rmax = fmaxf(rmax, __shfl_xor(rmax, 2));
            rmax = fmaxf(rmax, __shfl_xor(rmax, 4));
            rmax = fmaxf(rmax, __shfl_xor(rmax, 8));
            float mold = m_i[r];
            float mnew = fmaxf(mold, rmax);
            float alpha = __expf(mold - mnew);
            m_i[r] = mnew;
            float rsum = 0.f;
#pragma unroll
            for (int nt = 0; nt < 8; nt++) {
                float p = __expf(sc[nt][r] - mnew);
                sc[nt][r] = p;
                rsum += p;
            }
            rsum += __shfl_xor(rsum, 1);
            rsum += __shfl_xor(rsum, 2);
            rsum += __shfl_xor(rsum, 4);
            rsum += __shfl_xor(rsum, 8);
            l_i[r] = l_i[r] * alpha + rsum;
#pragma unroll
            for (int nt = 0; nt < 8; nt++) oa[nt][r] *= alpha;
        }
        // P -> per-wave LDS slab, swizzled (write then read, same wave: DS
        // ops are in-order per wave).
#pragma unroll
        for (int nt = 0; nt < 8; nt++)
#pragma unroll
            for (int r = 0; r < 4; r++) {
                int row = lquad * 4 + r;
                int col = nt * 16 + lrow;
                Pl[wave][row * 128 + (((col >> 3) ^ row) << 3) + (col & 7)] = (f16)sc[nt][r];
            }
        f16x8 pf[4];
#pragma unroll
        for (int ks = 0; ks < 4; ks++)
            pf[ks] = *(const f16x8*)(&Pl[wave][lrow * 128
                              + (((ks * 4 + lquad) ^ lrow) << 3)]);
#pragma unroll
        for (int nt = 0; nt < 8; nt++) {
#pragma unroll
            for (int ks = 0; ks < 4; ks++) {
                f16x8 vf = *(const f16x8*)(&Vs[buf][(nt * 16 + lrow) * 128
                                  + (((ks * 4 + lquad) ^ lrow) << 3)]);
                oa[nt] = __builtin_amdgcn_mfma_f32_16x16x32_f16(pf[ks], vf, oa[nt], 0, 0, 0);
            }
        }
        asm volatile("s_waitcnt lgkmcnt(0)" ::: "memory");  // reads retired (WAR)
        __builtin_amdgcn_s_barrier();
        buf ^= 1;
    }

    float inv[4];
#pragma unroll
    for (int r = 0; r < 4; r++) inv[r] = (l_i[r] > 0.f) ? 1.f / l_i[r] : 0.f;
#pragma unroll
    for (int nt = 0; nt < 8; nt++) {
#pragma unroll
        for (int r = 0; r < 4; r++) {
            int q = qw + lquad * 4 + r;
            int d = nt * 16 + lrow;
            int m = b * 2048 + q;
            int col = g * 128 + d;
            int p = m >> 6, r2 = m & 63;
            int tt = col >> 5;
            int cc = (col >> 3) & 3;
            size_t off = (((size_t)p * 16 + tt) * 64 + r2) * 32
                       + ((cc ^ ((r2 >> 1) & 3)) << 3) + (col & 7);
            AO[off] = (f16)(oa[nt][r] * inv[r]);
        }
    }
}

// ---------------------------------------------------------------------------
// Output GEMM: out = AO @ Wr^T + bo, f32 out. M=4096, N=2048, K=512.
// R12: 128x128 tile, 4 waves each 64x64 (8 ds_read / 16 MFMA per K-step).
// Grid 512 (32 by x 16 bx) = exactly 2 blocks/CU; LDS 4 x 16KB = 64KB.
// 4 linear DMA/thread/step; depth-3 prefetch; counted vmcnt(8)/(4)/(0).
// ---------------------------------------------------------------------------
__global__ __launch_bounds__(256)
void out_gemm(const f16* __restrict__ Ap, const f16* __restrict__ Bp,
              const float* __restrict__ bias, float* __restrict__ C)
{
    const int NSTEP = 16, N = 2048;
    __shared__ __align__(16) f16 S[4][8192];

    const int tid = threadIdx.x;
    const int wave = tid >> 6, lane = tid & 63;
    const int lrow = lane & 15, lquad = lane >> 4;
    const int wr = wave >> 1, wc = wave & 1;

    int id = (int)blockIdx.x;                 // 512 = 8 * 64
    int id2 = (id & 7) * 64 + (id >> 3);      // bijective XCD swizzle
    int bx = id2 & 15, by = id2 >> 4;         // bx 0..15, by 0..31
    const int m0 = by * 128, n0 = bx * 128;

    // staging: 1024 chunks/step = 4/thread. A rows 0..63 from panel 2by,
    // rows 64..127 from panel 2by+1; B = Wrp panel bx (512 chunks/ktile).
    const f16* gA0 = Ap + (size_t)(2 * by)     * 32768 + (size_t)tid * 8;
    const f16* gA1 = Ap + (size_t)(2 * by + 1) * 32768 + (size_t)tid * 8;
    const f16* gB0 = Bp + (size_t)bx * 65536 + (size_t)tid * 8;
    const f16* gB1 = Bp + (size_t)bx * 65536 + (size_t)(256 + tid) * 8;
    const int loA0 = tid * 8;
    const int loA1 = (256 + tid) * 8;
    const int loB0 = (512 + tid) * 8;
    const int loB1 = (768 + tid) * 8;

#define OSTAGE(t, buf)                                             \
    {                                                              \
        load_lds16(gA0 + (size_t)(t) * 2048, &S[buf][loA0]);       \
        load_lds16(gA1 + (size_t)(t) * 2048, &S[buf][loA1]);       \
        load_lds16(gB0 + (size_t)(t) * 4096, &S[buf][loB0]);       \
        load_lds16(gB1 + (size_t)(t) * 4096, &S[buf][loB1]);       \
    }

    // swizzled fragment read offsets (f16 units); B region starts at 4096
    int aoff[4], boff[4];
#pragma unroll
    for (int t = 0; t < 4; t++) {
        int ra = wr * 64 + t * 16 + lrow;
        aoff[t] = ra * 32 + ((lquad ^ ((ra >> 1) & 3)) << 3);
        int rb = wc * 64 + t * 16 + lrow;
        boff[t] = 4096 + rb * 32 + ((lquad ^ ((rb >> 1) & 3)) << 3);
    }

    f32x4 acc[4][4];
    const f32x4 z4 = {0.f, 0.f, 0.f, 0.f};
#pragma unroll
    for (int i = 0; i < 4; i++) for (int j = 0; j < 4; j++) acc[i][j] = z4;

    OSTAGE(0, 0); OSTAGE(1, 1); OSTAGE(2, 2);

    int buf = 0;
    for (int t = 0; t < NSTEP; ++t) {
        if (t < NSTEP - 2) {
            asm volatile("s_waitcnt vmcnt(8) lgkmcnt(0)" ::: "memory");
        } else if (t == NSTEP - 2) {
            asm volatile("s_waitcnt vmcnt(4) lgkmcnt(0)" ::: "memory");
        } else {
            asm volatile("s_waitcnt vmcnt(0) lgkmcnt(0)" ::: "memory");
        }
        __builtin_amdgcn_s_barrier();
        if (t < NSTEP - 3) OSTAGE(t + 3, (buf + 3) & 3);
        f16x8 af[4], bf[4];
#pragma unroll
        for (int mt = 0; mt < 4; mt++) af[mt] = *(const f16x8*)(&S[buf][aoff[mt]]);
#pragma unroll
        for (int nt = 0; nt < 4; nt++) bf[nt] = *(const f16x8*)(&S[buf][boff[nt]]);
#pragma unroll
        for (int mt = 0; mt < 4; mt++)
#pragma unroll
            for (int nt = 0; nt < 4; nt++)
                acc[mt][nt] = __builtin_amdgcn_mfma_f32_16x16x32_f16(af[mt], bf[nt], acc[mt][nt], 0, 0, 0);
        buf = (buf + 1) & 3;
    }

#pragma unroll
    for (int nt = 0; nt < 4; nt++) {
        int n = n0 + wc * 64 + nt * 16 + lrow;
        float bv2 = bias[n];
#pragma unroll
        for (int mt = 0; mt < 4; mt++) {
            int mbase = m0 + wr * 64 + mt * 16 + lquad * 4;
#pragma unroll
            for (int r = 0; r < 4; r++)
                C[(size_t)(mbase + r) * N + n] = acc[mt][nt][r] + bv2;
        }
    }
#undef OSTAGE
}

// ---------------------------------------------------------------------------
extern "C" void kernel_launch(void* const* d_in, const int* in_sizes, int n_in,
                              void* d_out, int out_size, void* d_ws, size_t ws_size,
                              hipStream_t stream)
{
    const float* x  = (const float*)d_in[0];
    const float* Wq = (const float*)d_in[1];
    const float* Wk = (const float*)d_in[2];
    const float* Wv = (const float*)d_in[3];
    const float* Wo = (const float*)d_in[4];
    const float* bo = (const float*)d_in[5];
    float* out = (float*)d_out;

    f16* Xp  = (f16*)d_ws;             // 8,388,608 (packed X) — dead after qkv
    f16* AO  = Xp;                     // alias: packed AO (2,097,152) reuses Xp
    f16* Wp  = Xp  + 8388608;          // 3,145,728 (packed Wq'|Wk|Wv)
    f16* Wrp = Wp  + 3145728;          // 1,048,576 (packed folded Wo)
    f16* Qws = Wrp + 1048576;          // 2,097,152 (B,4,S,D)
    f16* Kws = Qws + 2097152;          // 2,097,152 (attn-packed tiles)
    f16* Vws = Kws + 2097152;          // 2,097,152 (attn-packed tiles)
    // total 18,874,368 f16 = 36 MiB

    cvt_pack<<<dim3(6144), 256, 0, stream>>>(x, Wq, Wk, Wv, Wo, Xp, Wp, Wrp);
    qkv_gemm<<<dim3(768), 256, 0, stream>>>(Xp, Wp, Qws, Kws, Vws);
    attn_win<<<dim3(256), 256, 0, stream>>>(Qws, Kws, Vws, AO);
    out_gemm<<<dim3(512), 256, 0, stream>>>(AO, Wrp, bo, out);
}

// Round 8
// 175.622 us; speedup vs baseline: 1.0230x; 1.0230x over previous
//
#include <hip/hip_runtime.h>

typedef _Float16 f16;
typedef _Float16 f16x8 __attribute__((ext_vector_type(8)));
typedef _Float16 f16x4 __attribute__((ext_vector_type(4)));
typedef float    f32x4 __attribute__((ext_vector_type(4)));

// Problem: B=2, S=2048, E=2048, H=16, HKV=4, D=128, WINDOW=256
// Reference quirk: only q heads 0..3 used (q also indexed by idx); Wo pre-folds
// over the 4 heads per group: Wr[e,g*128+d] = sum_j Wo[e,(4g+j)*128+d].
//
// R13: R7 post-mortem: our kernels sum ~80us; rest is harness fill tax.
// Biggest controllable: qkv (~35us, 2x its L2-staging floor at 64x128).
// Change: qkv -> 128x128 tile (halves L2->LDS staging bytes per output;
// floor 18->12us), grid 384 (8x48 XCD swizzle), 4 waves x (4x4 frags,
// 16 MFMA : 8 ds_read), LDS 4x16KB, depth-3 prefetch, vmcnt(8)/(4)/(0).
// attn/out/cvt unchanged.

__device__ __forceinline__ void load_lds16(const void* g, void* l) {
    __builtin_amdgcn_global_load_lds(
        (__attribute__((address_space(1))) void*)(g),
        (__attribute__((address_space(3))) void*)(l), 16, 0, 0);
}

// ---------------------------------------------------------------------------
// Pre-pass: f32->f16 convert + pack.
//  blk [0,4096):    X  -> Xp  (64 panels x 64 ktiles, tile 64x32)
//  blk [4096,5632): W  -> Wp  (12 panels x 64 ktiles, tile 128x32)
//  blk [5632,6144): Wo -> Wrp (16 panels x 16 ktiles, tile 128x32, GQA-folded)
// ---------------------------------------------------------------------------
__global__ __launch_bounds__(256)
void cvt_pack(const float* __restrict__ X, const float* __restrict__ Wq,
              const float* __restrict__ Wk, const float* __restrict__ Wv,
              const float* __restrict__ Wo,
              f16* __restrict__ Xp, f16* __restrict__ Wp, f16* __restrict__ Wrp)
{
    const int blk = blockIdx.x, tid = threadIdx.x;
    if (blk < 4096) {
        int cid = blk * 256 + tid;
        int tile = cid >> 8, wc = cid & 255;
        int row = wc >> 2, kc = wc & 3;
        int m = ((tile >> 6) << 6) + row;
        int t = tile & 63;
        int sk = t * 32 + ((kc ^ ((row >> 1) & 3)) << 3);
        const float* s = X + (size_t)m * 2048 + sk;
        float4 a = *(const float4*)(s);
        float4 b = *(const float4*)(s + 4);
        f16x8 o;
        o[0]=(f16)a.x; o[1]=(f16)a.y; o[2]=(f16)a.z; o[3]=(f16)a.w;
        o[4]=(f16)b.x; o[5]=(f16)b.y; o[6]=(f16)b.z; o[7]=(f16)b.w;
        *(f16x8*)(Xp + (size_t)cid * 8) = o;
    } else if (blk < 5632) {
        int wid = (blk - 4096) * 256 + tid;
        int tile = wid >> 9, wc = wid & 511;
        int row = wc >> 2, kc = wc & 3;
        int n = ((tile >> 6) << 7) + row;
        int t = tile & 63;
        int sk = t * 32 + ((kc ^ ((row >> 1) & 3)) << 3);
        const float* src = (n < 512)  ? (Wq + (size_t)n * 2048 + sk)
                         : (n < 1024) ? (Wk + (size_t)(n - 512) * 2048 + sk)
                                      : (Wv + (size_t)(n - 1024) * 2048 + sk);
        float4 a = *(const float4*)(src);
        float4 b = *(const float4*)(src + 4);
        f16x8 o;
        o[0]=(f16)a.x; o[1]=(f16)a.y; o[2]=(f16)a.z; o[3]=(f16)a.w;
        o[4]=(f16)b.x; o[5]=(f16)b.y; o[6]=(f16)b.z; o[7]=(f16)b.w;
        *(f16x8*)(Wp + (size_t)wid * 8) = o;
    } else {
        int rid = (blk - 5632) * 256 + tid;
        int tile = rid >> 9, wc = rid & 511;
        int row = wc >> 2, kc = wc & 3;
        int e = ((tile >> 4) << 7) + row;
        int t = tile & 15;
        int cc = kc ^ ((row >> 1) & 3);
        int c = t * 32 + (cc << 3);
        int g = c >> 7, d0 = c & 127;
        const float* src = Wo + (size_t)e * 2048 + g * 512 + d0;
        float4 a0 = *(const float4*)(src);
        float4 a1 = *(const float4*)(src + 128);
        float4 a2 = *(const float4*)(src + 256);
        float4 a3 = *(const float4*)(src + 384);
        float4 b0 = *(const float4*)(src + 4);
        float4 b1 = *(const float4*)(src + 132);
        float4 b2 = *(const float4*)(src + 260);
        float4 b3 = *(const float4*)(src + 388);
        f16x8 o;
        o[0] = (f16)(a0.x + a1.x + a2.x + a3.x);
        o[1] = (f16)(a0.y + a1.y + a2.y + a3.y);
        o[2] = (f16)(a0.z + a1.z + a2.z + a3.z);
        o[3] = (f16)(a0.w + a1.w + a2.w + a3.w);
        o[4] = (f16)(b0.x + b1.x + b2.x + b3.x);
        o[5] = (f16)(b0.y + b1.y + b2.y + b3.y);
        o[6] = (f16)(b0.z + b1.z + b2.z + b3.z);
        o[7] = (f16)(b0.w + b1.w + b2.w + b3.w);
        *(f16x8*)(Wrp + (size_t)rid * 8) = o;
    }
}

// ---------------------------------------------------------------------------
// Merged QKV GEMM: M=4096, N=1536, K=2048. Packed inputs.
// R13: tile 128x128, grid 384 (8x48 swizzle), 4 waves each 64x64.
// LDS: A[128][32] then B[128][32] per buffer (16KB), 4 buffers.
// n block z = bx>>2 selects (Q | K | V); hh = bx&3.
// Packed K:  Kp[bg][t][s&127][ ((d>>3)^(s&15))*8 + (d&7) ]
// Packed V:  Vp[bg][t][d]    [ ((s7>>3)^(d&15))*8 + (s7&7) ]  (s7 = s&127)
// ---------------------------------------------------------------------------
__global__ __launch_bounds__(256)
void qkv_gemm(const f16* __restrict__ Xp, const f16* __restrict__ Wp,
              f16* __restrict__ Qo, f16* __restrict__ Ko, f16* __restrict__ Vo)
{
    const int NSTEP = 64;
    __shared__ __align__(16) f16 S[4][8192];

    const int tid = threadIdx.x;
    const int wave = tid >> 6, lane = tid & 63;
    const int lrow = lane & 15, lquad = lane >> 4;
    const int wr = wave >> 1, wc = wave & 1;

    int id = (int)blockIdx.x;                 // 384 = 8 * 48
    int id2 = (id & 7) * 48 + (id >> 3);      // bijective XCD swizzle
    int bx = id2 % 12, by = id2 / 12;         // bx 0..11, by 0..31
    const int m0 = by * 128;

    // staging: 1024 chunks/step = 4/thread. A rows 0..63 panel 2by,
    // rows 64..127 panel 2by+1; B = Wp panel bx (512 chunks/ktile).
    const f16* gA0 = Xp + (size_t)(2 * by)     * 131072 + (size_t)tid * 8;
    const f16* gA1 = Xp + (size_t)(2 * by + 1) * 131072 + (size_t)tid * 8;
    const f16* gB0 = Wp + (size_t)bx * 262144 + (size_t)tid * 8;
    const f16* gB1 = Wp + (size_t)bx * 262144 + (size_t)(256 + tid) * 8;
    const int loA0 = tid * 8;
    const int loA1 = (256 + tid) * 8;
    const int loB0 = (512 + tid) * 8;
    const int loB1 = (768 + tid) * 8;

#define QSTAGE(t, buf)                                             \
    {                                                              \
        load_lds16(gA0 + (size_t)(t) * 2048, &S[buf][loA0]);       \
        load_lds16(gA1 + (size_t)(t) * 2048, &S[buf][loA1]);       \
        load_lds16(gB0 + (size_t)(t) * 4096, &S[buf][loB0]);       \
        load_lds16(gB1 + (size_t)(t) * 4096, &S[buf][loB1]);       \
    }

    // swizzled fragment read offsets (f16 units); B region starts at 4096
    int aoff[4], boff[4];
#pragma unroll
    for (int t = 0; t < 4; t++) {
        int ra = wr * 64 + t * 16 + lrow;
        aoff[t] = ra * 32 + ((lquad ^ ((ra >> 1) & 3)) << 3);
        int rb = wc * 64 + t * 16 + lrow;
        boff[t] = 4096 + rb * 32 + ((lquad ^ ((rb >> 1) & 3)) << 3);
    }

    f32x4 acc[4][4];
    const f32x4 z4 = {0.f, 0.f, 0.f, 0.f};
#pragma unroll
    for (int i = 0; i < 4; i++) for (int j = 0; j < 4; j++) acc[i][j] = z4;

    QSTAGE(0, 0); QSTAGE(1, 1); QSTAGE(2, 2);

    int buf = 0;
    for (int t = 0; t < NSTEP; ++t) {
        if (t < NSTEP - 2) {
            asm volatile("s_waitcnt vmcnt(8) lgkmcnt(0)" ::: "memory");
        } else if (t == NSTEP - 2) {
            asm volatile("s_waitcnt vmcnt(4) lgkmcnt(0)" ::: "memory");
        } else {
            asm volatile("s_waitcnt vmcnt(0) lgkmcnt(0)" ::: "memory");
        }
        __builtin_amdgcn_s_barrier();
        if (t < NSTEP - 3) QSTAGE(t + 3, (buf + 3) & 3);
        f16x8 af[4], bf[4];
#pragma unroll
        for (int mt = 0; mt < 4; mt++) af[mt] = *(const f16x8*)(&S[buf][aoff[mt]]);
#pragma unroll
        for (int nt = 0; nt < 4; nt++) bf[nt] = *(const f16x8*)(&S[buf][boff[nt]]);
#pragma unroll
        for (int mt = 0; mt < 4; mt++)
#pragma unroll
            for (int nt = 0; nt < 4; nt++)
                acc[mt][nt] = __builtin_amdgcn_mfma_f32_16x16x32_f16(af[mt], bf[nt], acc[mt][nt], 0, 0, 0);
        buf = (buf + 1) & 3;
    }
#undef QSTAGE

    const int z = bx >> 2;
    const int hh = bx & 3;
    if (z == 0) {
        // Q: (B,4,S,D) row-major
#pragma unroll
        for (int mt = 0; mt < 4; mt++) {
            int mbase = m0 + wr * 64 + mt * 16 + lquad * 4;
#pragma unroll
            for (int r = 0; r < 4; r++) {
                int m = mbase + r;
                int bb = m >> 11, s = m & 2047;
#pragma unroll
                for (int nt = 0; nt < 4; nt++) {
                    int d = wc * 64 + nt * 16 + lrow;
                    Qo[(size_t)(((bb * 4 + hh) << 11) + s) * 128 + d] = (f16)acc[mt][nt][r];
                }
            }
        }
    } else if (z == 1) {
        // K: attn-packed swizzled tiles
#pragma unroll
        for (int mt = 0; mt < 4; mt++) {
            int mbase = m0 + wr * 64 + mt * 16 + lquad * 4;
#pragma unroll
            for (int r = 0; r < 4; r++) {
                int m = mbase + r;
                int bb = m >> 11, s = m & 2047;
                size_t base = ((size_t)(bb * 4 + hh) * 16 + (s >> 7)) * 16384
                            + (size_t)(s & 127) * 128;
#pragma unroll
                for (int nt = 0; nt < 4; nt++) {
                    int d = wc * 64 + nt * 16 + lrow;
                    Ko[base + (((d >> 3) ^ (s & 15)) << 3) + (d & 7)] = (f16)acc[mt][nt][r];
                }
            }
        }
    } else {
        // V: attn-packed swizzled tiles (f16x4 over 4 consecutive s)
#pragma unroll
        for (int mt = 0; mt < 4; mt++) {
            int mbase = m0 + wr * 64 + mt * 16 + lquad * 4;
            int bb = mbase >> 11, s = mbase & 2047;
            int tt = s >> 7, sl = s & 127;
            int gsx = sl >> 3, j0 = sl & 7;     // j0 in {0,4}; granule-constant
#pragma unroll
            for (int nt = 0; nt < 4; nt++) {
                int d = wc * 64 + nt * 16 + lrow;
                f16x4 pk;
#pragma unroll
                for (int r = 0; r < 4; r++) pk[r] = (f16)acc[mt][nt][r];
                *(f16x4*)(Vo + ((size_t)(bb * 4 + hh) * 16 + tt) * 16384
                             + (size_t)d * 128 + ((gsx ^ (d & 15)) << 3) + j0) = pk;
            }
        }
    }
}

// ---------------------------------------------------------------------------
// Sliding-window attention. 4 waves/block, 64 q-rows/block, one (b,g).
// Grid 256; bg = blockIdx.x & 7 pins each head to one XCD.
// K/V: packed swizzled 32KB tiles, staged as linear DMA, double-buffered.
// AO written in out_gemm's packed A layout.
// ---------------------------------------------------------------------------
__global__ __launch_bounds__(256)
void attn_win(const f16* __restrict__ Q, const f16* __restrict__ Kp,
              const f16* __restrict__ Vp, f16* __restrict__ AO)
{
    const int h = blockIdx.x;
    const int bg = h & 7, qt = h >> 3;
    const int b = bg >> 2, g = bg & 3;
    const int qbase = qt * 64;
    const int tid = threadIdx.x;
    const int wave = tid >> 6, lane = tid & 63;
    const int lrow = lane & 15, lquad = lane >> 4;
    const int qw = qbase + wave * 16;

    const f16* Qb = Q  + (size_t)bg * (2048 * 128);
    const f16* Kt = Kp + (size_t)bg * (2048 * 128);
    const f16* Vt = Vp + (size_t)bg * (2048 * 128);

    __shared__ __align__(16) f16 Ks[2][16384];
    __shared__ __align__(16) f16 Vs[2][16384];
    __shared__ __align__(16) f16 Pl[4][2048];

    f16x8 qf[4];
#pragma unroll
    for (int ks = 0; ks < 4; ks++)
        qf[ks] = *(const f16x8*)(Qb + (size_t)(qw + lrow) * 128 + ks * 32 + lquad * 8);

    float m_i[4], l_i[4];
    f32x4 oa[8];
    const f32x4 z4 = {0.f, 0.f, 0.f, 0.f};
#pragma unroll
    for (int r = 0; r < 4; r++) { m_i[r] = -30000.f; l_i[r] = 0.f; }
#pragma unroll
    for (int nt = 0; nt < 8; nt++) oa[nt] = z4;

    const int tstart = (qbase >= 256) ? ((qbase - 255) >> 7) : 0;
    const int tend = (qbase + 63) >> 7;

    {   // prologue: stage tile tstart into buf 0 (32 linear DMA instrs)
        const f16* ksrc = Kt + (size_t)tstart * 16384;
        const f16* vsrc = Vt + (size_t)tstart * 16384;
#pragma unroll
        for (int j = 0; j < 8; j++) {
            load_lds16(ksrc + (j * 256 + tid) * 8, &Ks[0][(j * 256 + tid) * 8]);
            load_lds16(vsrc + (j * 256 + tid) * 8, &Vs[0][(j * 256 + tid) * 8]);
        }
    }

    int buf = 0;
    for (int t = tstart; t <= tend; ++t) {
        if (t < tend) {       // prefetch next tile into other buffer
            const f16* ksrc = Kt + (size_t)(t + 1) * 16384;
            const f16* vsrc = Vt + (size_t)(t + 1) * 16384;
#pragma unroll
            for (int j = 0; j < 8; j++) {
                load_lds16(ksrc + (j * 256 + tid) * 8, &Ks[buf ^ 1][(j * 256 + tid) * 8]);
                load_lds16(vsrc + (j * 256 + tid) * 8, &Vs[buf ^ 1][(j * 256 + tid) * 8]);
            }
            asm volatile("s_waitcnt vmcnt(16)" ::: "memory");  // tile t ready
        } else {
            asm volatile("s_waitcnt vmcnt(0)" ::: "memory");
        }
        __builtin_amdgcn_s_barrier();

        const int kt = t * 128;
        f32x4 sc[8];
#pragma unroll
        for (int nt = 0; nt < 8; nt++) sc[nt] = z4;
#pragma unroll
        for (int nt = 0; nt < 8; nt++) {
#pragma unroll
            for (int ks = 0; ks < 4; ks++) {
                f16x8 kf = *(const f16x8*)(&Ks[buf][(nt * 16 + lrow) * 128
                                  + (((ks * 4 + lquad) ^ lrow) << 3)]);
                sc[nt] = __builtin_amdgcn_mfma_f32_16x16x32_f16(qf[ks], kf, sc[nt], 0, 0, 0);
            }
        }
#pragma unroll
        for (int r = 0; r < 4; r++) {
            const int qi = qw + lquad * 4 + r;
            float rmax = -60000.f;
#pragma unroll
            for (int nt = 0; nt < 8; nt++) {
                int kj = kt + nt * 16 + lrow;
                float sval = sc[nt][r];
                bool ok = (kj <= qi) && (kj + 256 > qi);
                sval = ok ? sval : -60000.f;
                sc[nt][r] = sval;
                rmax = fmaxf(rmax, sval);
            }
            rmax = fmaxf(rmax, __shfl_xor(rmax, 1));
            rmax = fmaxf(rmax, __shfl_xor(rmax, 2));
            rmax = fmaxf(rmax, __shfl_xor(rmax, 4));
            rmax = fmaxf(rmax, __shfl_xor(rmax, 8));
            float mold = m_i[r];
            float mnew = fmaxf(mold, rmax);
            float alpha = __expf(mold - mnew);
            m_i[r] = mnew;
            float rsum = 0.f;
#pragma unroll
            for (int nt = 0; nt < 8; nt++) {
                float p = __expf(sc[nt][r] - mnew);
                sc[nt][r] = p;
                rsum += p;
            }
            rsum += __shfl_xor(rsum, 1);
            rsum += __shfl_xor(rsum, 2);
            rsum += __shfl_xor(rsum, 4);
            rsum += __shfl_xor(rsum, 8);
            l_i[r] = l_i[r] * alpha + rsum;
#pragma unroll
            for (int nt = 0; nt < 8; nt++) oa[nt][r] *= alpha;
        }
        // P -> per-wave LDS slab, swizzled (write then read, same wave: DS
        // ops are in-order per wave).
#pragma unroll
        for (int nt = 0; nt < 8; nt++)
#pragma unroll
            for (int r = 0; r < 4; r++) {
                int row = lquad * 4 + r;
                int col = nt * 16 + lrow;
                Pl[wave][row * 128 + (((col >> 3) ^ row) << 3) + (col & 7)] = (f16)sc[nt][r];
            }
        f16x8 pf[4];
#pragma unroll
        for (int ks = 0; ks < 4; ks++)
            pf[ks] = *(const f16x8*)(&Pl[wave][lrow * 128
                              + (((ks * 4 + lquad) ^ lrow) << 3)]);
#pragma unroll
        for (int nt = 0; nt < 8; nt++) {
#pragma unroll
            for (int ks = 0; ks < 4; ks++) {
                f16x8 vf = *(const f16x8*)(&Vs[buf][(nt * 16 + lrow) * 128
                                  + (((ks * 4 + lquad) ^ lrow) << 3)]);
                oa[nt] = __builtin_amdgcn_mfma_f32_16x16x32_f16(pf[ks], vf, oa[nt], 0, 0, 0);
            }
        }
        asm volatile("s_waitcnt lgkmcnt(0)" ::: "memory");  // reads retired (WAR)
        __builtin_amdgcn_s_barrier();
        buf ^= 1;
    }

    float inv[4];
#pragma unroll
    for (int r = 0; r < 4; r++) inv[r] = (l_i[r] > 0.f) ? 1.f / l_i[r] : 0.f;
#pragma unroll
    for (int nt = 0; nt < 8; nt++) {
#pragma unroll
        for (int r = 0; r < 4; r++) {
            int q = qw + lquad * 4 + r;
            int d = nt * 16 + lrow;
            int m = b * 2048 + q;
            int col = g * 128 + d;
            int p = m >> 6, r2 = m & 63;
            int tt = col >> 5;
            int cc = (col >> 3) & 3;
            size_t off = (((size_t)p * 16 + tt) * 64 + r2) * 32
                       + ((cc ^ ((r2 >> 1) & 3)) << 3) + (col & 7);
            AO[off] = (f16)(oa[nt][r] * inv[r]);
        }
    }
}

// ---------------------------------------------------------------------------
// Output GEMM: out = AO @ Wr^T + bo, f32 out. M=4096, N=2048, K=512.
// 128x128 tile, 4 waves each 64x64; grid 512 (8x64 swizzle); LDS 4x16KB.
// ---------------------------------------------------------------------------
__global__ __launch_bounds__(256)
void out_gemm(const f16* __restrict__ Ap, const f16* __restrict__ Bp,
              const float* __restrict__ bias, float* __restrict__ C)
{
    const int NSTEP = 16, N = 2048;
    __shared__ __align__(16) f16 S[4][8192];

    const int tid = threadIdx.x;
    const int wave = tid >> 6, lane = tid & 63;
    const int lrow = lane & 15, lquad = lane >> 4;
    const int wr = wave >> 1, wc = wave & 1;

    int id = (int)blockIdx.x;                 // 512 = 8 * 64
    int id2 = (id & 7) * 64 + (id >> 3);      // bijective XCD swizzle
    int bx = id2 & 15, by = id2 >> 4;         // bx 0..15, by 0..31
    const int m0 = by * 128, n0 = bx * 128;

    const f16* gA0 = Ap + (size_t)(2 * by)     * 32768 + (size_t)tid * 8;
    const f16* gA1 = Ap + (size_t)(2 * by + 1) * 32768 + (size_t)tid * 8;
    const f16* gB0 = Bp + (size_t)bx * 65536 + (size_t)tid * 8;
    const f16* gB1 = Bp + (size_t)bx * 65536 + (size_t)(256 + tid) * 8;
    const int loA0 = tid * 8;
    const int loA1 = (256 + tid) * 8;
    const int loB0 = (512 + tid) * 8;
    const int loB1 = (768 + tid) * 8;

#define OSTAGE(t, buf)                                             \
    {                                                              \
        load_lds16(gA0 + (size_t)(t) * 2048, &S[buf][loA0]);       \
        load_lds16(gA1 + (size_t)(t) * 2048, &S[buf][loA1]);       \
        load_lds16(gB0 + (size_t)(t) * 4096, &S[buf][loB0]);       \
        load_lds16(gB1 + (size_t)(t) * 4096, &S[buf][loB1]);       \
    }

    int aoff[4], boff[4];
#pragma unroll
    for (int t = 0; t < 4; t++) {
        int ra = wr * 64 + t * 16 + lrow;
        aoff[t] = ra * 32 + ((lquad ^ ((ra >> 1) & 3)) << 3);
        int rb = wc * 64 + t * 16 + lrow;
        boff[t] = 4096 + rb * 32 + ((lquad ^ ((rb >> 1) & 3)) << 3);
    }

    f32x4 acc[4][4];
    const f32x4 z4 = {0.f, 0.f, 0.f, 0.f};
#pragma unroll
    for (int i = 0; i < 4; i++) for (int j = 0; j < 4; j++) acc[i][j] = z4;

    OSTAGE(0, 0); OSTAGE(1, 1); OSTAGE(2, 2);

    int buf = 0;
    for (int t = 0; t < NSTEP; ++t) {
        if (t < NSTEP - 2) {
            asm volatile("s_waitcnt vmcnt(8) lgkmcnt(0)" ::: "memory");
        } else if (t == NSTEP - 2) {
            asm volatile("s_waitcnt vmcnt(4) lgkmcnt(0)" ::: "memory");
        } else {
            asm volatile("s_waitcnt vmcnt(0) lgkmcnt(0)" ::: "memory");
        }
        __builtin_amdgcn_s_barrier();
        if (t < NSTEP - 3) OSTAGE(t + 3, (buf + 3) & 3);
        f16x8 af[4], bf[4];
#pragma unroll
        for (int mt = 0; mt < 4; mt++) af[mt] = *(const f16x8*)(&S[buf][aoff[mt]]);
#pragma unroll
        for (int nt = 0; nt < 4; nt++) bf[nt] = *(const f16x8*)(&S[buf][boff[nt]]);
#pragma unroll
        for (int mt = 0; mt < 4; mt++)
#pragma unroll
            for (int nt = 0; nt < 4; nt++)
                acc[mt][nt] = __builtin_amdgcn_mfma_f32_16x16x32_f16(af[mt], bf[nt], acc[mt][nt], 0, 0, 0);
        buf = (buf + 1) & 3;
    }

#pragma unroll
    for (int nt = 0; nt < 4; nt++) {
        int n = n0 + wc * 64 + nt * 16 + lrow;
        float bv2 = bias[n];
#pragma unroll
        for (int mt = 0; mt < 4; mt++) {
            int mbase = m0 + wr * 64 + mt * 16 + lquad * 4;
#pragma unroll
            for (int r = 0; r < 4; r++)
                C[(size_t)(mbase + r) * N + n] = acc[mt][nt][r] + bv2;
        }
    }
#undef OSTAGE
}

// ---------------------------------------------------------------------------
extern "C" void kernel_launch(void* const* d_in, const int* in_sizes, int n_in,
                              void* d_out, int out_size, void* d_ws, size_t ws_size,
                              hipStream_t stream)
{
    const float* x  = (const float*)d_in[0];
    const float* Wq = (const float*)d_in[1];
    const float* Wk = (const float*)d_in[2];
    const float* Wv = (const float*)d_in[3];
    const float* Wo = (const float*)d_in[4];
    const float* bo = (const float*)d_in[5];
    float* out = (float*)d_out;

    f16* Xp  = (f16*)d_ws;             // 8,388,608 (packed X) — dead after qkv
    f16* AO  = Xp;                     // alias: packed AO (2,097,152) reuses Xp
    f16* Wp  = Xp  + 8388608;          // 3,145,728 (packed Wq'|Wk|Wv)
    f16* Wrp = Wp  + 3145728;          // 1,048,576 (packed folded Wo)
    f16* Qws = Wrp + 1048576;          // 2,097,152 (B,4,S,D)
    f16* Kws = Qws + 2097152;          // 2,097,152 (attn-packed tiles)
    f16* Vws = Kws + 2097152;          // 2,097,152 (attn-packed tiles)
    // total 18,874,368 f16 = 36 MiB

    cvt_pack<<<dim3(6144), 256, 0, stream>>>(x, Wq, Wk, Wv, Wo, Xp, Wp, Wrp);
    qkv_gemm<<<dim3(384), 256, 0, stream>>>(Xp, Wp, Qws, Kws, Vws);
    attn_win<<<dim3(256), 256, 0, stream>>>(Qws, Kws, Vws, AO);
    out_gemm<<<dim3(512), 256, 0, stream>>>(AO, Wrp, bo, out);
}

// Round 9
// 175.123 us; speedup vs baseline: 1.0259x; 1.0028x over previous
//
#include <hip/hip_runtime.h>

typedef _Float16 f16;
typedef _Float16 f16x8 __attribute__((ext_vector_type(8)));
typedef _Float16 f16x4 __attribute__((ext_vector_type(4)));
typedef float    f32x4 __attribute__((ext_vector_type(4)));

// Problem: B=2, S=2048, E=2048, H=16, HKV=4, D=128, WINDOW=256
// Reference quirk: only q heads 0..3 used (q also indexed by idx); Wo pre-folds
// over the 4 heads per group: Wr[e,g*128+d] = sum_j Wo[e,(4g+j)*128+d].
//
// R14: attn was 1 wave/SIMD (1024 waves) -> serial QK/softmax/PV chains
// exposed (17us vs ~3us work). Rewrite: 256 blocks x 8 waves (512 thr),
// each 16-row q-group owned by a wave PAIR splitting 64-key KV tiles
// even/odd (flash-decoding), merged via LDS at end. 2 waves/SIMD.
// KVBLK=64: Ks[2][2][8192]+Vs[2][2][8192]+Pl[8][1024] = 144KB, 1 blk/CU.
// V packed layout -> 64-key tiles (qkv epilogue change); K 64-tiles are
// halves of the existing 128-tiles (address-only). Lockstep barriers:
// I=ceil(T/2) uniform; staging clamped to t1 keeps DMA counts uniform.

__device__ __forceinline__ void load_lds16(const void* g, void* l) {
    __builtin_amdgcn_global_load_lds(
        (__attribute__((address_space(1))) void*)(g),
        (__attribute__((address_space(3))) void*)(l), 16, 0, 0);
}

// ---------------------------------------------------------------------------
// Pre-pass: f32->f16 convert + pack (unchanged).
// ---------------------------------------------------------------------------
__global__ __launch_bounds__(256)
void cvt_pack(const float* __restrict__ X, const float* __restrict__ Wq,
              const float* __restrict__ Wk, const float* __restrict__ Wv,
              const float* __restrict__ Wo,
              f16* __restrict__ Xp, f16* __restrict__ Wp, f16* __restrict__ Wrp)
{
    const int blk = blockIdx.x, tid = threadIdx.x;
    if (blk < 4096) {
        int cid = blk * 256 + tid;
        int tile = cid >> 8, wc = cid & 255;
        int row = wc >> 2, kc = wc & 3;
        int m = ((tile >> 6) << 6) + row;
        int t = tile & 63;
        int sk = t * 32 + ((kc ^ ((row >> 1) & 3)) << 3);
        const float* s = X + (size_t)m * 2048 + sk;
        float4 a = *(const float4*)(s);
        float4 b = *(const float4*)(s + 4);
        f16x8 o;
        o[0]=(f16)a.x; o[1]=(f16)a.y; o[2]=(f16)a.z; o[3]=(f16)a.w;
        o[4]=(f16)b.x; o[5]=(f16)b.y; o[6]=(f16)b.z; o[7]=(f16)b.w;
        *(f16x8*)(Xp + (size_t)cid * 8) = o;
    } else if (blk < 5632) {
        int wid = (blk - 4096) * 256 + tid;
        int tile = wid >> 9, wc = wid & 511;
        int row = wc >> 2, kc = wc & 3;
        int n = ((tile >> 6) << 7) + row;
        int t = tile & 63;
        int sk = t * 32 + ((kc ^ ((row >> 1) & 3)) << 3);
        const float* src = (n < 512)  ? (Wq + (size_t)n * 2048 + sk)
                         : (n < 1024) ? (Wk + (size_t)(n - 512) * 2048 + sk)
                                      : (Wv + (size_t)(n - 1024) * 2048 + sk);
        float4 a = *(const float4*)(src);
        float4 b = *(const float4*)(src + 4);
        f16x8 o;
        o[0]=(f16)a.x; o[1]=(f16)a.y; o[2]=(f16)a.z; o[3]=(f16)a.w;
        o[4]=(f16)b.x; o[5]=(f16)b.y; o[6]=(f16)b.z; o[7]=(f16)b.w;
        *(f16x8*)(Wp + (size_t)wid * 8) = o;
    } else {
        int rid = (blk - 5632) * 256 + tid;
        int tile = rid >> 9, wc = rid & 511;
        int row = wc >> 2, kc = wc & 3;
        int e = ((tile >> 4) << 7) + row;
        int t = tile & 15;
        int cc = kc ^ ((row >> 1) & 3);
        int c = t * 32 + (cc << 3);
        int g = c >> 7, d0 = c & 127;
        const float* src = Wo + (size_t)e * 2048 + g * 512 + d0;
        float4 a0 = *(const float4*)(src);
        float4 a1 = *(const float4*)(src + 128);
        float4 a2 = *(const float4*)(src + 256);
        float4 a3 = *(const float4*)(src + 384);
        float4 b0 = *(const float4*)(src + 4);
        float4 b1 = *(const float4*)(src + 132);
        float4 b2 = *(const float4*)(src + 260);
        float4 b3 = *(const float4*)(src + 388);
        f16x8 o;
        o[0] = (f16)(a0.x + a1.x + a2.x + a3.x);
        o[1] = (f16)(a0.y + a1.y + a2.y + a3.y);
        o[2] = (f16)(a0.z + a1.z + a2.z + a3.z);
        o[3] = (f16)(a0.w + a1.w + a2.w + a3.w);
        o[4] = (f16)(b0.x + b1.x + b2.x + b3.x);
        o[5] = (f16)(b0.y + b1.y + b2.y + b3.y);
        o[6] = (f16)(b0.z + b1.z + b2.z + b3.z);
        o[7] = (f16)(b0.w + b1.w + b2.w + b3.w);
        *(f16x8*)(Wrp + (size_t)rid * 8) = o;
    }
}

// ---------------------------------------------------------------------------
// Merged QKV GEMM: M=4096, N=1536, K=2048. 128x128 tile, grid 384 (8x48).
// z = bx>>2 selects (Q | K | V); hh = bx&3.
// Packed K (128-key tiles): Kp[bg][t7][s&127][ ((d>>3)^(s&15))*8 + (d&7) ]
// Packed V (64-key tiles):  Vp[bg][t6][d][ ((s6>>3)^(d&7))*8 + (s6&7) ]
// ---------------------------------------------------------------------------
__global__ __launch_bounds__(256)
void qkv_gemm(const f16* __restrict__ Xp, const f16* __restrict__ Wp,
              f16* __restrict__ Qo, f16* __restrict__ Ko, f16* __restrict__ Vo)
{
    const int NSTEP = 64;
    __shared__ __align__(16) f16 S[4][8192];

    const int tid = threadIdx.x;
    const int wave = tid >> 6, lane = tid & 63;
    const int lrow = lane & 15, lquad = lane >> 4;
    const int wr = wave >> 1, wc = wave & 1;

    int id = (int)blockIdx.x;                 // 384 = 8 * 48
    int id2 = (id & 7) * 48 + (id >> 3);      // bijective XCD swizzle
    int bx = id2 % 12, by = id2 / 12;
    const int m0 = by * 128;

    const f16* gA0 = Xp + (size_t)(2 * by)     * 131072 + (size_t)tid * 8;
    const f16* gA1 = Xp + (size_t)(2 * by + 1) * 131072 + (size_t)tid * 8;
    const f16* gB0 = Wp + (size_t)bx * 262144 + (size_t)tid * 8;
    const f16* gB1 = Wp + (size_t)bx * 262144 + (size_t)(256 + tid) * 8;
    const int loA0 = tid * 8;
    const int loA1 = (256 + tid) * 8;
    const int loB0 = (512 + tid) * 8;
    const int loB1 = (768 + tid) * 8;

#define QSTAGE(t, buf)                                             \
    {                                                              \
        load_lds16(gA0 + (size_t)(t) * 2048, &S[buf][loA0]);       \
        load_lds16(gA1 + (size_t)(t) * 2048, &S[buf][loA1]);       \
        load_lds16(gB0 + (size_t)(t) * 4096, &S[buf][loB0]);       \
        load_lds16(gB1 + (size_t)(t) * 4096, &S[buf][loB1]);       \
    }

    int aoff[4], boff[4];
#pragma unroll
    for (int t = 0; t < 4; t++) {
        int ra = wr * 64 + t * 16 + lrow;
        aoff[t] = ra * 32 + ((lquad ^ ((ra >> 1) & 3)) << 3);
        int rb = wc * 64 + t * 16 + lrow;
        boff[t] = 4096 + rb * 32 + ((lquad ^ ((rb >> 1) & 3)) << 3);
    }

    f32x4 acc[4][4];
    const f32x4 z4 = {0.f, 0.f, 0.f, 0.f};
#pragma unroll
    for (int i = 0; i < 4; i++) for (int j = 0; j < 4; j++) acc[i][j] = z4;

    QSTAGE(0, 0); QSTAGE(1, 1); QSTAGE(2, 2);

    int buf = 0;
    for (int t = 0; t < NSTEP; ++t) {
        if (t < NSTEP - 2) {
            asm volatile("s_waitcnt vmcnt(8) lgkmcnt(0)" ::: "memory");
        } else if (t == NSTEP - 2) {
            asm volatile("s_waitcnt vmcnt(4) lgkmcnt(0)" ::: "memory");
        } else {
            asm volatile("s_waitcnt vmcnt(0) lgkmcnt(0)" ::: "memory");
        }
        __builtin_amdgcn_s_barrier();
        if (t < NSTEP - 3) QSTAGE(t + 3, (buf + 3) & 3);
        f16x8 af[4], bf[4];
#pragma unroll
        for (int mt = 0; mt < 4; mt++) af[mt] = *(const f16x8*)(&S[buf][aoff[mt]]);
#pragma unroll
        for (int nt = 0; nt < 4; nt++) bf[nt] = *(const f16x8*)(&S[buf][boff[nt]]);
#pragma unroll
        for (int mt = 0; mt < 4; mt++)
#pragma unroll
            for (int nt = 0; nt < 4; nt++)
                acc[mt][nt] = __builtin_amdgcn_mfma_f32_16x16x32_f16(af[mt], bf[nt], acc[mt][nt], 0, 0, 0);
        buf = (buf + 1) & 3;
    }
#undef QSTAGE

    const int z = bx >> 2;
    const int hh = bx & 3;
    if (z == 0) {
        // Q: (B,4,S,D) row-major
#pragma unroll
        for (int mt = 0; mt < 4; mt++) {
            int mbase = m0 + wr * 64 + mt * 16 + lquad * 4;
#pragma unroll
            for (int r = 0; r < 4; r++) {
                int m = mbase + r;
                int bb = m >> 11, s = m & 2047;
#pragma unroll
                for (int nt = 0; nt < 4; nt++) {
                    int d = wc * 64 + nt * 16 + lrow;
                    Qo[(size_t)(((bb * 4 + hh) << 11) + s) * 128 + d] = (f16)acc[mt][nt][r];
                }
            }
        }
    } else if (z == 1) {
        // K: 128-key packed tiles
#pragma unroll
        for (int mt = 0; mt < 4; mt++) {
            int mbase = m0 + wr * 64 + mt * 16 + lquad * 4;
#pragma unroll
            for (int r = 0; r < 4; r++) {
                int m = mbase + r;
                int bb = m >> 11, s = m & 2047;
                size_t base = ((size_t)(bb * 4 + hh) * 16 + (s >> 7)) * 16384
                            + (size_t)(s & 127) * 128;
#pragma unroll
                for (int nt = 0; nt < 4; nt++) {
                    int d = wc * 64 + nt * 16 + lrow;
                    Ko[base + (((d >> 3) ^ (s & 15)) << 3) + (d & 7)] = (f16)acc[mt][nt][r];
                }
            }
        }
    } else {
        // V: 64-key packed tiles [d][s6 swizzled] (f16x4 over 4 consecutive s)
#pragma unroll
        for (int mt = 0; mt < 4; mt++) {
            int mbase = m0 + wr * 64 + mt * 16 + lquad * 4;
            int bb = mbase >> 11, s = mbase & 2047;
            int tt = s >> 6, sl = s & 63;
            int gsx = sl >> 3, j0 = sl & 7;     // j0 in {0,4}
#pragma unroll
            for (int nt = 0; nt < 4; nt++) {
                int d = wc * 64 + nt * 16 + lrow;
                f16x4 pk;
#pragma unroll
                for (int r = 0; r < 4; r++) pk[r] = (f16)acc[mt][nt][r];
                *(f16x4*)(Vo + ((size_t)(bb * 4 + hh) * 32 + tt) * 8192
                             + (size_t)d * 64 + ((gsx ^ (d & 7)) << 3) + j0) = pk;
            }
        }
    }
}

// ---------------------------------------------------------------------------
// Sliding-window attention, KV-split. 8 waves (512 thr), 64 q-rows/block.
// wave = qg*2 + hf: q-group qg (16 rows), half hf splits 64-key tiles
// even/odd; lockstep I=ceil(T/2) iterations; merge via LDS at end.
// Grid 256; bg = blockIdx.x & 7 pins each head to one XCD.
// ---------------------------------------------------------------------------
__global__ __launch_bounds__(512, 2)
void attn_win(const f16* __restrict__ Q, const f16* __restrict__ Kp,
              const f16* __restrict__ Vp, f16* __restrict__ AO)
{
    const int hblk = blockIdx.x;
    const int bg = hblk & 7, qt = hblk >> 3;
    const int b = bg >> 2, g = bg & 3;
    const int qbase = qt * 64;
    const int tid = threadIdx.x;
    const int wave = tid >> 6, lane = tid & 63;
    const int lrow = lane & 15, lquad = lane >> 4;
    const int qg = wave >> 1, hf = wave & 1;
    const int qw = qbase + qg * 16;

    const f16* Qb = Q  + (size_t)bg * (2048 * 128);
    const f16* Kt = Kp + (size_t)bg * 262144;
    const f16* Vt = Vp + (size_t)bg * 262144;

    __shared__ __align__(16) f16 Ks[2][2][8192];   // [half][dbuf] 64x128 keysxd
    __shared__ __align__(16) f16 Vs[2][2][8192];   // [half][dbuf] 128x64 dxkeys
    __shared__ __align__(16) f16 Pl[8][1024];      // per-wave P 16x64

    f16x8 qf[4];
#pragma unroll
    for (int ks = 0; ks < 4; ks++)
        qf[ks] = *(const f16x8*)(Qb + (size_t)(qw + lrow) * 128 + ks * 32 + lquad * 8);

    float m_i[4], l_i[4];
    f32x4 oa[8];
    const f32x4 z4 = {0.f, 0.f, 0.f, 0.f};
#pragma unroll
    for (int r = 0; r < 4; r++) { m_i[r] = -30000.f; l_i[r] = 0.f; }
#pragma unroll
    for (int nt = 0; nt < 8; nt++) oa[nt] = z4;

    const int t0v = (qbase >= 256) ? ((qbase - 255) >> 6) : 0;
    const int t1v = (qbase + 63) >> 6;          // qbase/64
    const int T = t1v - t0v + 1;                // <= 5
    const int I = (T + 1) >> 1;                 // <= 3

    const int c0 = (wave * 64 + lane) * 8;      // chunk offsets (f16 units)
    const int c1 = c0 + 4096;

    // Stage pair p = tiles (t0v+2p [half0], t0v+2p+1 [half1]), clamped to t1v
    // so DMA counts stay uniform. 8 DMA/thread/pair.
#define APAIR(p, bufi)                                                         \
    {                                                                          \
        int tA = t0v + 2 * (p);  if (tA > t1v) tA = t1v;                       \
        int tB = tA + 1;         if (tB > t1v) tB = t1v;                       \
        const f16* kA = Kt + (size_t)(tA >> 1) * 16384 + (size_t)(tA & 1) * 8192; \
        const f16* vA = Vt + (size_t)tA * 8192;                                \
        const f16* kB = Kt + (size_t)(tB >> 1) * 16384 + (size_t)(tB & 1) * 8192; \
        const f16* vB = Vt + (size_t)tB * 8192;                                \
        load_lds16(kA + c0, &Ks[0][bufi][c0]);                                 \
        load_lds16(kA + c1, &Ks[0][bufi][c1]);                                 \
        load_lds16(vA + c0, &Vs[0][bufi][c0]);                                 \
        load_lds16(vA + c1, &Vs[0][bufi][c1]);                                 \
        load_lds16(kB + c0, &Ks[1][bufi][c0]);                                 \
        load_lds16(kB + c1, &Ks[1][bufi][c1]);                                 \
        load_lds16(vB + c0, &Vs[1][bufi][c0]);                                 \
        load_lds16(vB + c1, &Vs[1][bufi][c1]);                                 \
    }

    APAIR(0, 0);
    APAIR(1, 1);

    int bufc = 0;
    for (int i = 0; i < I; ++i) {
        if (i < I - 1) asm volatile("s_waitcnt vmcnt(8)" ::: "memory");
        else           asm volatile("s_waitcnt vmcnt(0)" ::: "memory");
        __builtin_amdgcn_s_barrier();

        const int t = t0v + 2 * i + hf;
        if (t <= t1v) {
            const int kt = t * 64;
            f32x4 sc[4];
#pragma unroll
            for (int nt = 0; nt < 4; nt++) sc[nt] = z4;
#pragma unroll
            for (int nt = 0; nt < 4; nt++) {
#pragma unroll
                for (int ks = 0; ks < 4; ks++) {
                    f16x8 kf = *(const f16x8*)(&Ks[hf][bufc][(nt * 16 + lrow) * 128
                                      + (((ks * 4 + lquad) ^ lrow) << 3)]);
                    sc[nt] = __builtin_amdgcn_mfma_f32_16x16x32_f16(qf[ks], kf, sc[nt], 0, 0, 0);
                }
            }
#pragma unroll
            for (int r = 0; r < 4; r++) {
                const int qi = qw + lquad * 4 + r;
                float rmax = -60000.f;
#pragma unroll
                for (int nt = 0; nt < 4; nt++) {
                    int kj = kt + nt * 16 + lrow;
                    float sval = sc[nt][r];
                    bool ok = (kj <= qi) && (kj + 256 > qi);
                    sval = ok ? sval : -60000.f;
                    sc[nt][r] = sval;
                    rmax = fmaxf(rmax, sval);
                }
                rmax = fmaxf(rmax, __shfl_xor(rmax, 1));
                rmax = fmaxf(rmax, __shfl_xor(rmax, 2));
                rmax = fmaxf(rmax, __shfl_xor(rmax, 4));
                rmax = fmaxf(rmax, __shfl_xor(rmax, 8));
                float mold = m_i[r];
                float mnew = fmaxf(mold, rmax);
                float alpha = __expf(mold - mnew);
                m_i[r] = mnew;
                float rsum = 0.f;
#pragma unroll
                for (int nt = 0; nt < 4; nt++) {
                    float p = __expf(sc[nt][r] - mnew);
                    sc[nt][r] = p;
                    rsum += p;
                }
                rsum += __shfl_xor(rsum, 1);
                rsum += __shfl_xor(rsum, 2);
                rsum += __shfl_xor(rsum, 4);
                rsum += __shfl_xor(rsum, 8);
                l_i[r] = l_i[r] * alpha + rsum;
#pragma unroll
                for (int nt = 0; nt < 8; nt++) oa[nt][r] *= alpha;
            }
            // P -> per-wave swizzled slab (16 rows x 64 keys)
#pragma unroll
            for (int nt = 0; nt < 4; nt++)
#pragma unroll
                for (int r = 0; r < 4; r++) {
                    int row = lquad * 4 + r;
                    Pl[wave][row * 64 + (((nt * 2 + (lrow >> 3)) ^ (row & 7)) << 3)
                             + (lrow & 7)] = (f16)sc[nt][r];
                }
            f16x8 pf[2];
#pragma unroll
            for (int ks = 0; ks < 2; ks++)
                pf[ks] = *(const f16x8*)(&Pl[wave][lrow * 64
                                  + (((ks * 4 + lquad) ^ (lrow & 7)) << 3)]);
#pragma unroll
            for (int nt = 0; nt < 8; nt++) {
#pragma unroll
                for (int ks = 0; ks < 2; ks++) {
                    int dv = nt * 16 + lrow;
                    f16x8 vf = *(const f16x8*)(&Vs[hf][bufc][dv * 64
                                      + (((ks * 4 + lquad) ^ (dv & 7)) << 3)]);
                    oa[nt] = __builtin_amdgcn_mfma_f32_16x16x32_f16(pf[ks], vf, oa[nt], 0, 0, 0);
                }
            }
        }
        asm volatile("s_waitcnt lgkmcnt(0)" ::: "memory");   // reads retired (WAR)
        __builtin_amdgcn_s_barrier();
        if (i + 2 < I) APAIR(i + 2, bufc);
        bufc ^= 1;
    }
#undef APAIR

    // ---- merge halves (reuse Ks region as f32 scratch) ----
    float* mrg = (float*)&Ks[0][0][0];
    if (hf == 1) {
#pragma unroll
        for (int r = 0; r < 4; r++) {
            int row = lquad * 4 + r;
            if (lrow == 0) {
                mrg[qg * 16 + row] = m_i[r];
                mrg[64 + qg * 16 + row] = l_i[r];
            }
#pragma unroll
            for (int nt = 0; nt < 8; nt++)
                mrg[128 + qg * 2048 + row * 128 + nt * 16 + lrow] = oa[nt][r];
        }
    }
    asm volatile("s_waitcnt lgkmcnt(0)" ::: "memory");
    __builtin_amdgcn_s_barrier();
    if (hf == 0) {
#pragma unroll
        for (int r = 0; r < 4; r++) {
            int row = lquad * 4 + r;
            float m1 = mrg[qg * 16 + row];
            float l1 = mrg[64 + qg * 16 + row];
            float mm = fmaxf(m_i[r], m1);
            float a0 = __expf(m_i[r] - mm);
            float a1 = __expf(m1 - mm);
            float ll = l_i[r] * a0 + l1 * a1;
            float inv = (ll > 0.f) ? 1.f / ll : 0.f;
            int q = qw + row;
            int m = b * 2048 + q;
            int p = m >> 6, r2 = m & 63;
#pragma unroll
            for (int nt = 0; nt < 8; nt++) {
                int d = nt * 16 + lrow;
                float o1 = mrg[128 + qg * 2048 + row * 128 + d];
                float od = (oa[nt][r] * a0 + o1 * a1) * inv;
                int col = g * 128 + d;
                int tt = col >> 5;
                int cc = (col >> 3) & 3;
                size_t off = (((size_t)p * 16 + tt) * 64 + r2) * 32
                           + ((cc ^ ((r2 >> 1) & 3)) << 3) + (col & 7);
                AO[off] = (f16)od;
            }
        }
    }
}

// ---------------------------------------------------------------------------
// Output GEMM: out = AO @ Wr^T + bo, f32 out. M=4096, N=2048, K=512.
// 128x128 tile, 4 waves each 64x64; grid 512 (8x64 swizzle); LDS 4x16KB.
// ---------------------------------------------------------------------------
__global__ __launch_bounds__(256)
void out_gemm(const f16* __restrict__ Ap, const f16* __restrict__ Bp,
              const float* __restrict__ bias, float* __restrict__ C)
{
    const int NSTEP = 16, N = 2048;
    __shared__ __align__(16) f16 S[4][8192];

    const int tid = threadIdx.x;
    const int wave = tid >> 6, lane = tid & 63;
    const int lrow = lane & 15, lquad = lane >> 4;
    const int wr = wave >> 1, wc = wave & 1;

    int id = (int)blockIdx.x;                 // 512 = 8 * 64
    int id2 = (id & 7) * 64 + (id >> 3);      // bijective XCD swizzle
    int bx = id2 & 15, by = id2 >> 4;
    const int m0 = by * 128, n0 = bx * 128;

    const f16* gA0 = Ap + (size_t)(2 * by)     * 32768 + (size_t)tid * 8;
    const f16* gA1 = Ap + (size_t)(2 * by + 1) * 32768 + (size_t)tid * 8;
    const f16* gB0 = Bp + (size_t)bx * 65536 + (size_t)tid * 8;
    const f16* gB1 = Bp + (size_t)bx * 65536 + (size_t)(256 + tid) * 8;
    const int loA0 = tid * 8;
    const int loA1 = (256 + tid) * 8;
    const int loB0 = (512 + tid) * 8;
    const int loB1 = (768 + tid) * 8;

#define OSTAGE(t, buf)                                             \
    {                                                              \
        load_lds16(gA0 + (size_t)(t) * 2048, &S[buf][loA0]);       \
        load_lds16(gA1 + (size_t)(t) * 2048, &S[buf][loA1]);       \
        load_lds16(gB0 + (size_t)(t) * 4096, &S[buf][loB0]);       \
        load_lds16(gB1 + (size_t)(t) * 4096, &S[buf][loB1]);       \
    }

    int aoff[4], boff[4];
#pragma unroll
    for (int t = 0; t < 4; t++) {
        int ra = wr * 64 + t * 16 + lrow;
        aoff[t] = ra * 32 + ((lquad ^ ((ra >> 1) & 3)) << 3);
        int rb = wc * 64 + t * 16 + lrow;
        boff[t] = 4096 + rb * 32 + ((lquad ^ ((rb >> 1) & 3)) << 3);
    }

    f32x4 acc[4][4];
    const f32x4 z4 = {0.f, 0.f, 0.f, 0.f};
#pragma unroll
    for (int i = 0; i < 4; i++) for (int j = 0; j < 4; j++) acc[i][j] = z4;

    OSTAGE(0, 0); OSTAGE(1, 1); OSTAGE(2, 2);

    int buf = 0;
    for (int t = 0; t < NSTEP; ++t) {
        if (t < NSTEP - 2) {
            asm volatile("s_waitcnt vmcnt(8) lgkmcnt(0)" ::: "memory");
        } else if (t == NSTEP - 2) {
            asm volatile("s_waitcnt vmcnt(4) lgkmcnt(0)" ::: "memory");
        } else {
            asm volatile("s_waitcnt vmcnt(0) lgkmcnt(0)" ::: "memory");
        }
        __builtin_amdgcn_s_barrier();
        if (t < NSTEP - 3) OSTAGE(t + 3, (buf + 3) & 3);
        f16x8 af[4], bf[4];
#pragma unroll
        for (int mt = 0; mt < 4; mt++) af[mt] = *(const f16x8*)(&S[buf][aoff[mt]]);
#pragma unroll
        for (int nt = 0; nt < 4; nt++) bf[nt] = *(const f16x8*)(&S[buf][boff[nt]]);
#pragma unroll
        for (int mt = 0; mt < 4; mt++)
#pragma unroll
            for (int nt = 0; nt < 4; nt++)
                acc[mt][nt] = __builtin_amdgcn_mfma_f32_16x16x32_f16(af[mt], bf[nt], acc[mt][nt], 0, 0, 0);
        buf = (buf + 1) & 3;
    }

#pragma unroll
    for (int nt = 0; nt < 4; nt++) {
        int n = n0 + wc * 64 + nt * 16 + lrow;
        float bv2 = bias[n];
#pragma unroll
        for (int mt = 0; mt < 4; mt++) {
            int mbase = m0 + wr * 64 + mt * 16 + lquad * 4;
#pragma unroll
            for (int r = 0; r < 4; r++)
                C[(size_t)(mbase + r) * N + n] = acc[mt][nt][r] + bv2;
        }
    }
#undef OSTAGE
}

// ---------------------------------------------------------------------------
extern "C" void kernel_launch(void* const* d_in, const int* in_sizes, int n_in,
                              void* d_out, int out_size, void* d_ws, size_t ws_size,
                              hipStream_t stream)
{
    const float* x  = (const float*)d_in[0];
    const float* Wq = (const float*)d_in[1];
    const float* Wk = (const float*)d_in[2];
    const float* Wv = (const float*)d_in[3];
    const float* Wo = (const float*)d_in[4];
    const float* bo = (const float*)d_in[5];
    float* out = (float*)d_out;

    f16* Xp  = (f16*)d_ws;             // 8,388,608 (packed X) — dead after qkv
    f16* AO  = Xp;                     // alias: packed AO (2,097,152) reuses Xp
    f16* Wp  = Xp  + 8388608;          // 3,145,728 (packed Wq'|Wk|Wv)
    f16* Wrp = Wp  + 3145728;          // 1,048,576 (packed folded Wo)
    f16* Qws = Wrp + 1048576;          // 2,097,152 (B,4,S,D)
    f16* Kws = Qws + 2097152;          // 2,097,152 (128-key packed tiles)
    f16* Vws = Kws + 2097152;          // 2,097,152 (64-key packed tiles)
    // total 18,874,368 f16 = 36 MiB

    cvt_pack<<<dim3(6144), 256, 0, stream>>>(x, Wq, Wk, Wv, Wo, Xp, Wp, Wrp);
    qkv_gemm<<<dim3(384), 256, 0, stream>>>(Xp, Wp, Qws, Kws, Vws);
    attn_win<<<dim3(256), 512, 0, stream>>>(Qws, Kws, Vws, AO);
    out_gemm<<<dim3(512), 256, 0, stream>>>(AO, Wrp, bo, out);
}

// Round 10
// 174.169 us; speedup vs baseline: 1.0315x; 1.0055x over previous
//
#include <hip/hip_runtime.h>

typedef _Float16 f16;
typedef _Float16 f16x8 __attribute__((ext_vector_type(8)));
typedef _Float16 f16x4 __attribute__((ext_vector_type(4)));
typedef float    f32x4 __attribute__((ext_vector_type(4)));

// Problem: B=2, S=2048, E=2048, H=16, HKV=4, D=128, WINDOW=256
// Reference quirk: only q heads 0..3 used (q also indexed by idx); Wo pre-folds
// over the 4 heads per group: Wr[e,g*128+d] = sum_j Wo[e,(4g+j)*128+d].
//
// R15: qkv is staging-DMA-bound (~1000cy/step vs ~130 compute) and 384-block
// grid is imbalanced (1.5 blocks/CU, LDS-capped 2). Tile 128x192 -> grid
// 256 = exactly 1 block/CU, staging/output -17%, per-XCD W slab (768KB)
// L2-resident via bx = XCD id. 4 waves x 64x96 (24 MFMA : 10 ds_read),
// LDS 4x20KB, 5 DMA/thread/step, depth-3 vmcnt(10)/(5)/(0).
// attn (R14 KV-split) / out_gemm / cvt frozen.

__device__ __forceinline__ void load_lds16(const void* g, void* l) {
    __builtin_amdgcn_global_load_lds(
        (__attribute__((address_space(1))) void*)(g),
        (__attribute__((address_space(3))) void*)(l), 16, 0, 0);
}

// ---------------------------------------------------------------------------
// Pre-pass: f32->f16 convert + pack (unchanged).
// ---------------------------------------------------------------------------
__global__ __launch_bounds__(256)
void cvt_pack(const float* __restrict__ X, const float* __restrict__ Wq,
              const float* __restrict__ Wk, const float* __restrict__ Wv,
              const float* __restrict__ Wo,
              f16* __restrict__ Xp, f16* __restrict__ Wp, f16* __restrict__ Wrp)
{
    const int blk = blockIdx.x, tid = threadIdx.x;
    if (blk < 4096) {
        int cid = blk * 256 + tid;
        int tile = cid >> 8, wc = cid & 255;
        int row = wc >> 2, kc = wc & 3;
        int m = ((tile >> 6) << 6) + row;
        int t = tile & 63;
        int sk = t * 32 + ((kc ^ ((row >> 1) & 3)) << 3);
        const float* s = X + (size_t)m * 2048 + sk;
        float4 a = *(const float4*)(s);
        float4 b = *(const float4*)(s + 4);
        f16x8 o;
        o[0]=(f16)a.x; o[1]=(f16)a.y; o[2]=(f16)a.z; o[3]=(f16)a.w;
        o[4]=(f16)b.x; o[5]=(f16)b.y; o[6]=(f16)b.z; o[7]=(f16)b.w;
        *(f16x8*)(Xp + (size_t)cid * 8) = o;
    } else if (blk < 5632) {
        int wid = (blk - 4096) * 256 + tid;
        int tile = wid >> 9, wc = wid & 511;
        int row = wc >> 2, kc = wc & 3;
        int n = ((tile >> 6) << 7) + row;
        int t = tile & 63;
        int sk = t * 32 + ((kc ^ ((row >> 1) & 3)) << 3);
        const float* src = (n < 512)  ? (Wq + (size_t)n * 2048 + sk)
                         : (n < 1024) ? (Wk + (size_t)(n - 512) * 2048 + sk)
                                      : (Wv + (size_t)(n - 1024) * 2048 + sk);
        float4 a = *(const float4*)(src);
        float4 b = *(const float4*)(src + 4);
        f16x8 o;
        o[0]=(f16)a.x; o[1]=(f16)a.y; o[2]=(f16)a.z; o[3]=(f16)a.w;
        o[4]=(f16)b.x; o[5]=(f16)b.y; o[6]=(f16)b.z; o[7]=(f16)b.w;
        *(f16x8*)(Wp + (size_t)wid * 8) = o;
    } else {
        int rid = (blk - 5632) * 256 + tid;
        int tile = rid >> 9, wc = rid & 511;
        int row = wc >> 2, kc = wc & 3;
        int e = ((tile >> 4) << 7) + row;
        int t = tile & 15;
        int cc = kc ^ ((row >> 1) & 3);
        int c = t * 32 + (cc << 3);
        int g = c >> 7, d0 = c & 127;
        const float* src = Wo + (size_t)e * 2048 + g * 512 + d0;
        float4 a0 = *(const float4*)(src);
        float4 a1 = *(const float4*)(src + 128);
        float4 a2 = *(const float4*)(src + 256);
        float4 a3 = *(const float4*)(src + 384);
        float4 b0 = *(const float4*)(src + 4);
        float4 b1 = *(const float4*)(src + 132);
        float4 b2 = *(const float4*)(src + 260);
        float4 b3 = *(const float4*)(src + 388);
        f16x8 o;
        o[0] = (f16)(a0.x + a1.x + a2.x + a3.x);
        o[1] = (f16)(a0.y + a1.y + a2.y + a3.y);
        o[2] = (f16)(a0.z + a1.z + a2.z + a3.z);
        o[3] = (f16)(a0.w + a1.w + a2.w + a3.w);
        o[4] = (f16)(b0.x + b1.x + b2.x + b3.x);
        o[5] = (f16)(b0.y + b1.y + b2.y + b3.y);
        o[6] = (f16)(b0.z + b1.z + b2.z + b3.z);
        o[7] = (f16)(b0.w + b1.w + b2.w + b3.w);
        *(f16x8*)(Wrp + (size_t)rid * 8) = o;
    }
}

// ---------------------------------------------------------------------------
// Merged QKV GEMM: M=4096, N=1536, K=2048. Tile 128x192, grid 256 (1/CU).
// bx = XCD id (0..7): 192-col W slab per XCD, L2-resident. by = id>>3.
// LDS per buffer: A[128][32] (4096 f16) + B[192][32] (6144 f16) = 20KB.
// Per-fragment epilogue: n = bx*192 + wc*96 + nt*16 + lrow; z=n>>9 selects
// Q/K/V; fragments are 16-wide and never cross 128-col head boundaries.
// Packed K (128-key tiles): Kp[bg][t7][s&127][ ((d>>3)^(s&15))*8 + (d&7) ]
// Packed V (64-key tiles):  Vp[bg][t6][d][ ((s6>>3)^(d&7))*8 + (s6&7) ]
// ---------------------------------------------------------------------------
__global__ __launch_bounds__(256)
void qkv_gemm(const f16* __restrict__ Xp, const f16* __restrict__ Wp,
              f16* __restrict__ Qo, f16* __restrict__ Ko, f16* __restrict__ Vo)
{
    const int NSTEP = 64;
    __shared__ __align__(16) f16 S[4][10240];

    const int tid = threadIdx.x;
    const int wave = tid >> 6, lane = tid & 63;
    const int lrow = lane & 15, lquad = lane >> 4;
    const int wr = wave >> 1, wc = wave & 1;

    const int id = (int)blockIdx.x;           // 256 blocks
    const int bx = id & 7;                    // = XCD id -> W slab locality
    const int by = id >> 3;                   // 0..31
    const int m0 = by * 128;

    // 1280 chunks/step = 5/thread. Slot c = (wave*5+j)*64 + lane.
    // c < 512: A (Xp panels 2by, 2by+1); else B rows bx*192 + (c-512)/4,
    // crossing 128-row Wp panels (per-lane panel addressing; swizzle key
    // (n>>1)&3 is bx*192-invariant since 192*bx has no bits < 6... (bits>=6,
    // >>1 -> >=5, &3 = 0)).
    const f16* gs[5]; int st[5]; int lo[5];
#pragma unroll
    for (int j = 0; j < 5; j++) {
        int c = (wave * 5 + j) * 64 + lane;
        lo[j] = c * 8;
        if (c < 512) {
            gs[j] = Xp + (size_t)(2 * by + (c >> 8)) * 131072 + (size_t)(c & 255) * 8;
            st[j] = 2048;
        } else {
            int cb = c - 512;
            int rb = cb >> 2, kc = cb & 3;
            int n = bx * 192 + rb;
            gs[j] = Wp + (size_t)(n >> 7) * 262144 + (size_t)((n & 127) * 32 + kc * 8);
            st[j] = 4096;
        }
    }

#define QSTAGE(t, buf)                                                  \
    {                                                                   \
        _Pragma("unroll")                                               \
        for (int j = 0; j < 5; j++)                                     \
            load_lds16(gs[j] + (size_t)(t) * st[j], &S[buf][lo[j]]);    \
    }

    // fragment read offsets (f16 units); B region starts at 4096
    int aoff[4], boff[6];
#pragma unroll
    for (int t = 0; t < 4; t++) {
        int ra = wr * 64 + t * 16 + lrow;
        aoff[t] = ra * 32 + ((lquad ^ ((ra >> 1) & 3)) << 3);
    }
#pragma unroll
    for (int t = 0; t < 6; t++) {
        int rb = wc * 96 + t * 16 + lrow;
        boff[t] = 4096 + rb * 32 + ((lquad ^ ((rb >> 1) & 3)) << 3);
    }

    f32x4 acc[4][6];
    const f32x4 z4 = {0.f, 0.f, 0.f, 0.f};
#pragma unroll
    for (int i = 0; i < 4; i++) for (int j = 0; j < 6; j++) acc[i][j] = z4;

    QSTAGE(0, 0); QSTAGE(1, 1); QSTAGE(2, 2);

    int buf = 0;
    for (int t = 0; t < NSTEP; ++t) {
        if (t < NSTEP - 2) {
            asm volatile("s_waitcnt vmcnt(10) lgkmcnt(0)" ::: "memory");
        } else if (t == NSTEP - 2) {
            asm volatile("s_waitcnt vmcnt(5) lgkmcnt(0)" ::: "memory");
        } else {
            asm volatile("s_waitcnt vmcnt(0) lgkmcnt(0)" ::: "memory");
        }
        __builtin_amdgcn_s_barrier();
        if (t < NSTEP - 3) QSTAGE(t + 3, (buf + 3) & 3);
        f16x8 af[4], bf[6];
#pragma unroll
        for (int mt = 0; mt < 4; mt++) af[mt] = *(const f16x8*)(&S[buf][aoff[mt]]);
#pragma unroll
        for (int nt = 0; nt < 6; nt++) bf[nt] = *(const f16x8*)(&S[buf][boff[nt]]);
#pragma unroll
        for (int mt = 0; mt < 4; mt++)
#pragma unroll
            for (int nt = 0; nt < 6; nt++)
                acc[mt][nt] = __builtin_amdgcn_mfma_f32_16x16x32_f16(af[mt], bf[nt], acc[mt][nt], 0, 0, 0);
        buf = (buf + 1) & 3;
    }
#undef QSTAGE

    // epilogue: resolve destination per 16-col fragment
#pragma unroll
    for (int nt = 0; nt < 6; nt++) {
        const int n = bx * 192 + wc * 96 + nt * 16 + lrow;
        const int z = n >> 9;
        const int hh = (n >> 7) & 3;
        const int d = n & 127;
        if (z == 0) {
#pragma unroll
            for (int mt = 0; mt < 4; mt++) {
                int mbase = m0 + wr * 64 + mt * 16 + lquad * 4;
#pragma unroll
                for (int r = 0; r < 4; r++) {
                    int m = mbase + r;
                    int bb = m >> 11, s = m & 2047;
                    Qo[(size_t)(((bb * 4 + hh) << 11) + s) * 128 + d] = (f16)acc[mt][nt][r];
                }
            }
        } else if (z == 1) {
#pragma unroll
            for (int mt = 0; mt < 4; mt++) {
                int mbase = m0 + wr * 64 + mt * 16 + lquad * 4;
#pragma unroll
                for (int r = 0; r < 4; r++) {
                    int m = mbase + r;
                    int bb = m >> 11, s = m & 2047;
                    size_t base = ((size_t)(bb * 4 + hh) * 16 + (s >> 7)) * 16384
                                + (size_t)(s & 127) * 128;
                    Ko[base + (((d >> 3) ^ (s & 15)) << 3) + (d & 7)] = (f16)acc[mt][nt][r];
                }
            }
        } else {
#pragma unroll
            for (int mt = 0; mt < 4; mt++) {
                int mbase = m0 + wr * 64 + mt * 16 + lquad * 4;
                int bb = mbase >> 11, s = mbase & 2047;
                int tt = s >> 6, sl = s & 63;
                int gsx = sl >> 3, j0 = sl & 7;     // j0 in {0,4}
                f16x4 pk;
#pragma unroll
                for (int r = 0; r < 4; r++) pk[r] = (f16)acc[mt][nt][r];
                *(f16x4*)(Vo + ((size_t)(bb * 4 + hh) * 32 + tt) * 8192
                             + (size_t)d * 64 + ((gsx ^ (d & 7)) << 3) + j0) = pk;
            }
        }
    }
}

// ---------------------------------------------------------------------------
// Sliding-window attention, KV-split (unchanged from R14).
// 8 waves (512 thr), 64 q-rows/block; wave pair splits 64-key tiles
// even/odd; lockstep I=ceil(T/2); merge via LDS. Grid 256; bg pins XCD.
// ---------------------------------------------------------------------------
__global__ __launch_bounds__(512, 2)
void attn_win(const f16* __restrict__ Q, const f16* __restrict__ Kp,
              const f16* __restrict__ Vp, f16* __restrict__ AO)
{
    const int hblk = blockIdx.x;
    const int bg = hblk & 7, qt = hblk >> 3;
    const int b = bg >> 2, g = bg & 3;
    const int qbase = qt * 64;
    const int tid = threadIdx.x;
    const int wave = tid >> 6, lane = tid & 63;
    const int lrow = lane & 15, lquad = lane >> 4;
    const int qg = wave >> 1, hf = wave & 1;
    const int qw = qbase + qg * 16;

    const f16* Qb = Q  + (size_t)bg * (2048 * 128);
    const f16* Kt = Kp + (size_t)bg * 262144;
    const f16* Vt = Vp + (size_t)bg * 262144;

    __shared__ __align__(16) f16 Ks[2][2][8192];
    __shared__ __align__(16) f16 Vs[2][2][8192];
    __shared__ __align__(16) f16 Pl[8][1024];

    f16x8 qf[4];
#pragma unroll
    for (int ks = 0; ks < 4; ks++)
        qf[ks] = *(const f16x8*)(Qb + (size_t)(qw + lrow) * 128 + ks * 32 + lquad * 8);

    float m_i[4], l_i[4];
    f32x4 oa[8];
    const f32x4 z4 = {0.f, 0.f, 0.f, 0.f};
#pragma unroll
    for (int r = 0; r < 4; r++) { m_i[r] = -30000.f; l_i[r] = 0.f; }
#pragma unroll
    for (int nt = 0; nt < 8; nt++) oa[nt] = z4;

    const int t0v = (qbase >= 256) ? ((qbase - 255) >> 6) : 0;
    const int t1v = (qbase + 63) >> 6;
    const int T = t1v - t0v + 1;
    const int I = (T + 1) >> 1;

    const int c0 = (wave * 64 + lane) * 8;
    const int c1 = c0 + 4096;

#define APAIR(p, bufi)                                                         \
    {                                                                          \
        int tA = t0v + 2 * (p);  if (tA > t1v) tA = t1v;                       \
        int tB = tA + 1;         if (tB > t1v) tB = t1v;                       \
        const f16* kA = Kt + (size_t)(tA >> 1) * 16384 + (size_t)(tA & 1) * 8192; \
        const f16* vA = Vt + (size_t)tA * 8192;                                \
        const f16* kB = Kt + (size_t)(tB >> 1) * 16384 + (size_t)(tB & 1) * 8192; \
        const f16* vB = Vt + (size_t)tB * 8192;                                \
        load_lds16(kA + c0, &Ks[0][bufi][c0]);                                 \
        load_lds16(kA + c1, &Ks[0][bufi][c1]);                                 \
        load_lds16(vA + c0, &Vs[0][bufi][c0]);                                 \
        load_lds16(vA + c1, &Vs[0][bufi][c1]);                                 \
        load_lds16(kB + c0, &Ks[1][bufi][c0]);                                 \
        load_lds16(kB + c1, &Ks[1][bufi][c1]);                                 \
        load_lds16(vB + c0, &Vs[1][bufi][c0]);                                 \
        load_lds16(vB + c1, &Vs[1][bufi][c1]);                                 \
    }

    APAIR(0, 0);
    APAIR(1, 1);

    int bufc = 0;
    for (int i = 0; i < I; ++i) {
        if (i < I - 1) asm volatile("s_waitcnt vmcnt(8)" ::: "memory");
        else           asm volatile("s_waitcnt vmcnt(0)" ::: "memory");
        __builtin_amdgcn_s_barrier();

        const int t = t0v + 2 * i + hf;
        if (t <= t1v) {
            const int kt = t * 64;
            f32x4 sc[4];
#pragma unroll
            for (int nt = 0; nt < 4; nt++) sc[nt] = z4;
#pragma unroll
            for (int nt = 0; nt < 4; nt++) {
#pragma unroll
                for (int ks = 0; ks < 4; ks++) {
                    f16x8 kf = *(const f16x8*)(&Ks[hf][bufc][(nt * 16 + lrow) * 128
                                      + (((ks * 4 + lquad) ^ lrow) << 3)]);
                    sc[nt] = __builtin_amdgcn_mfma_f32_16x16x32_f16(qf[ks], kf, sc[nt], 0, 0, 0);
                }
            }
#pragma unroll
            for (int r = 0; r < 4; r++) {
                const int qi = qw + lquad * 4 + r;
                float rmax = -60000.f;
#pragma unroll
                for (int nt = 0; nt < 4; nt++) {
                    int kj = kt + nt * 16 + lrow;
                    float sval = sc[nt][r];
                    bool ok = (kj <= qi) && (kj + 256 > qi);
                    sval = ok ? sval : -60000.f;
                    sc[nt][r] = sval;
                    rmax = fmaxf(rmax, sval);
                }
                rmax = fmaxf(rmax, __shfl_xor(rmax, 1));
                rmax = fmaxf(rmax, __shfl_xor(rmax, 2));
                rmax = fmaxf(rmax, __shfl_xor(rmax, 4));
                rmax = fmaxf(rmax, __shfl_xor(rmax, 8));
                float mold = m_i[r];
                float mnew = fmaxf(mold, rmax);
                float alpha = __expf(mold - mnew);
                m_i[r] = mnew;
                float rsum = 0.f;
#pragma unroll
                for (int nt = 0; nt < 4; nt++) {
                    float p = __expf(sc[nt][r] - mnew);
                    sc[nt][r] = p;
                    rsum += p;
                }
                rsum += __shfl_xor(rsum, 1);
                rsum += __shfl_xor(rsum, 2);
                rsum += __shfl_xor(rsum, 4);
                rsum += __shfl_xor(rsum, 8);
                l_i[r] = l_i[r] * alpha + rsum;
#pragma unroll
                for (int nt = 0; nt < 8; nt++) oa[nt][r] *= alpha;
            }
#pragma unroll
            for (int nt = 0; nt < 4; nt++)
#pragma unroll
                for (int r = 0; r < 4; r++) {
                    int row = lquad * 4 + r;
                    Pl[wave][row * 64 + (((nt * 2 + (lrow >> 3)) ^ (row & 7)) << 3)
                             + (lrow & 7)] = (f16)sc[nt][r];
                }
            f16x8 pf[2];
#pragma unroll
            for (int ks = 0; ks < 2; ks++)
                pf[ks] = *(const f16x8*)(&Pl[wave][lrow * 64
                                  + (((ks * 4 + lquad) ^ (lrow & 7)) << 3)]);
#pragma unroll
            for (int nt = 0; nt < 8; nt++) {
#pragma unroll
                for (int ks = 0; ks < 2; ks++) {
                    int dv = nt * 16 + lrow;
                    f16x8 vf = *(const f16x8*)(&Vs[hf][bufc][dv * 64
                                      + (((ks * 4 + lquad) ^ (dv & 7)) << 3)]);
                    oa[nt] = __builtin_amdgcn_mfma_f32_16x16x32_f16(pf[ks], vf, oa[nt], 0, 0, 0);
                }
            }
        }
        asm volatile("s_waitcnt lgkmcnt(0)" ::: "memory");
        __builtin_amdgcn_s_barrier();
        if (i + 2 < I) APAIR(i + 2, bufc);
        bufc ^= 1;
    }
#undef APAIR

    float* mrg = (float*)&Ks[0][0][0];
    if (hf == 1) {
#pragma unroll
        for (int r = 0; r < 4; r++) {
            int row = lquad * 4 + r;
            if (lrow == 0) {
                mrg[qg * 16 + row] = m_i[r];
                mrg[64 + qg * 16 + row] = l_i[r];
            }
#pragma unroll
            for (int nt = 0; nt < 8; nt++)
                mrg[128 + qg * 2048 + row * 128 + nt * 16 + lrow] = oa[nt][r];
        }
    }
    asm volatile("s_waitcnt lgkmcnt(0)" ::: "memory");
    __builtin_amdgcn_s_barrier();
    if (hf == 0) {
#pragma unroll
        for (int r = 0; r < 4; r++) {
            int row = lquad * 4 + r;
            float m1 = mrg[qg * 16 + row];
            float l1 = mrg[64 + qg * 16 + row];
            float mm = fmaxf(m_i[r], m1);
            float a0 = __expf(m_i[r] - mm);
            float a1 = __expf(m1 - mm);
            float ll = l_i[r] * a0 + l1 * a1;
            float inv = (ll > 0.f) ? 1.f / ll : 0.f;
            int q = qw + row;
            int m = b * 2048 + q;
            int p = m >> 6, r2 = m & 63;
#pragma unroll
            for (int nt = 0; nt < 8; nt++) {
                int d = nt * 16 + lrow;
                float o1 = mrg[128 + qg * 2048 + row * 128 + d];
                float od = (oa[nt][r] * a0 + o1 * a1) * inv;
                int col = g * 128 + d;
                int tt = col >> 5;
                int cc = (col >> 3) & 3;
                size_t off = (((size_t)p * 16 + tt) * 64 + r2) * 32
                           + ((cc ^ ((r2 >> 1) & 3)) << 3) + (col & 7);
                AO[off] = (f16)od;
            }
        }
    }
}

// ---------------------------------------------------------------------------
// Output GEMM: out = AO @ Wr^T + bo, f32 out. M=4096, N=2048, K=512.
// 128x128 tile, 4 waves each 64x64; grid 512 (8x64 swizzle); LDS 4x16KB.
// ---------------------------------------------------------------------------
__global__ __launch_bounds__(256)
void out_gemm(const f16* __restrict__ Ap, const f16* __restrict__ Bp,
              const float* __restrict__ bias, float* __restrict__ C)
{
    const int NSTEP = 16, N = 2048;
    __shared__ __align__(16) f16 S[4][8192];

    const int tid = threadIdx.x;
    const int wave = tid >> 6, lane = tid & 63;
    const int lrow = lane & 15, lquad = lane >> 4;
    const int wr = wave >> 1, wc = wave & 1;

    int id = (int)blockIdx.x;                 // 512 = 8 * 64
    int id2 = (id & 7) * 64 + (id >> 3);      // bijective XCD swizzle
    int bx = id2 & 15, by = id2 >> 4;
    const int m0 = by * 128, n0 = bx * 128;

    const f16* gA0 = Ap + (size_t)(2 * by)     * 32768 + (size_t)tid * 8;
    const f16* gA1 = Ap + (size_t)(2 * by + 1) * 32768 + (size_t)tid * 8;
    const f16* gB0 = Bp + (size_t)bx * 65536 + (size_t)tid * 8;
    const f16* gB1 = Bp + (size_t)bx * 65536 + (size_t)(256 + tid) * 8;
    const int loA0 = tid * 8;
    const int loA1 = (256 + tid) * 8;
    const int loB0 = (512 + tid) * 8;
    const int loB1 = (768 + tid) * 8;

#define OSTAGE(t, buf)                                             \
    {                                                              \
        load_lds16(gA0 + (size_t)(t) * 2048, &S[buf][loA0]);       \
        load_lds16(gA1 + (size_t)(t) * 2048, &S[buf][loA1]);       \
        load_lds16(gB0 + (size_t)(t) * 4096, &S[buf][loB0]);       \
        load_lds16(gB1 + (size_t)(t) * 4096, &S[buf][loB1]);       \
    }

    int aoff[4], boff[4];
#pragma unroll
    for (int t = 0; t < 4; t++) {
        int ra = wr * 64 + t * 16 + lrow;
        aoff[t] = ra * 32 + ((lquad ^ ((ra >> 1) & 3)) << 3);
        int rb = wc * 64 + t * 16 + lrow;
        boff[t] = 4096 + rb * 32 + ((lquad ^ ((rb >> 1) & 3)) << 3);
    }

    f32x4 acc[4][4];
    const f32x4 z4 = {0.f, 0.f, 0.f, 0.f};
#pragma unroll
    for (int i = 0; i < 4; i++) for (int j = 0; j < 4; j++) acc[i][j] = z4;

    OSTAGE(0, 0); OSTAGE(1, 1); OSTAGE(2, 2);

    int buf = 0;
    for (int t = 0; t < NSTEP; ++t) {
        if (t < NSTEP - 2) {
            asm volatile("s_waitcnt vmcnt(8) lgkmcnt(0)" ::: "memory");
        } else if (t == NSTEP - 2) {
            asm volatile("s_waitcnt vmcnt(4) lgkmcnt(0)" ::: "memory");
        } else {
            asm volatile("s_waitcnt vmcnt(0) lgkmcnt(0)" ::: "memory");
        }
        __builtin_amdgcn_s_barrier();
        if (t < NSTEP - 3) OSTAGE(t + 3, (buf + 3) & 3);
        f16x8 af[4], bf[4];
#pragma unroll
        for (int mt = 0; mt < 4; mt++) af[mt] = *(const f16x8*)(&S[buf][aoff[mt]]);
#pragma unroll
        for (int nt = 0; nt < 4; nt++) bf[nt] = *(const f16x8*)(&S[buf][boff[nt]]);
#pragma unroll
        for (int mt = 0; mt < 4; mt++)
#pragma unroll
            for (int nt = 0; nt < 4; nt++)
                acc[mt][nt] = __builtin_amdgcn_mfma_f32_16x16x32_f16(af[mt], bf[nt], acc[mt][nt], 0, 0, 0);
        buf = (buf + 1) & 3;
    }

#pragma unroll
    for (int nt = 0; nt < 4; nt++) {
        int n = n0 + wc * 64 + nt * 16 + lrow;
        float bv2 = bias[n];
#pragma unroll
        for (int mt = 0; mt < 4; mt++) {
            int mbase = m0 + wr * 64 + mt * 16 + lquad * 4;
#pragma unroll
            for (int r = 0; r < 4; r++)
                C[(size_t)(mbase + r) * N + n] = acc[mt][nt][r] + bv2;
        }
    }
#undef OSTAGE
}

// ---------------------------------------------------------------------------
extern "C" void kernel_launch(void* const* d_in, const int* in_sizes, int n_in,
                              void* d_out, int out_size, void* d_ws, size_t ws_size,
                              hipStream_t stream)
{
    const float* x  = (const float*)d_in[0];
    const float* Wq = (const float*)d_in[1];
    const float* Wk = (const float*)d_in[2];
    const float* Wv = (const float*)d_in[3];
    const float* Wo = (const float*)d_in[4];
    const float* bo = (const float*)d_in[5];
    float* out = (float*)d_out;

    f16* Xp  = (f16*)d_ws;             // 8,388,608 (packed X) — dead after qkv
    f16* AO  = Xp;                     // alias: packed AO (2,097,152) reuses Xp
    f16* Wp  = Xp  + 8388608;          // 3,145,728 (packed Wq'|Wk|Wv)
    f16* Wrp = Wp  + 3145728;          // 1,048,576 (packed folded Wo)
    f16* Qws = Wrp + 1048576;          // 2,097,152 (B,4,S,D)
    f16* Kws = Qws + 2097152;          // 2,097,152 (128-key packed tiles)
    f16* Vws = Kws + 2097152;          // 2,097,152 (64-key packed tiles)
    // total 18,874,368 f16 = 36 MiB

    cvt_pack<<<dim3(6144), 256, 0, stream>>>(x, Wq, Wk, Wv, Wo, Xp, Wp, Wrp);
    qkv_gemm<<<dim3(256), 256, 0, stream>>>(Xp, Wp, Qws, Kws, Vws);
    attn_win<<<dim3(256), 512, 0, stream>>>(Qws, Kws, Vws, AO);
    out_gemm<<<dim3(512), 256, 0, stream>>>(AO, Wrp, bo, out);
}